// Round 3
// baseline (9335.403 us; speedup 1.0000x reference)
//
#include <hip/hip_runtime.h>

// LAS decoder, dtype-adaptive (fp32 or bf16 inputs, probed on device via
// x_mask[0] as u32: fp32 1.0f = 0x3F800000, bf16 pair = 0x3F803F80).
// Round 8: fix R7's register-pin spill. R7 intended to pin each block's
// step-invariant Ta row-slice (16 uint4) and eout column-slice (64 u32) in
// VGPRs, but the er_r load loop used "#pragma unroll 8" (PARTIAL unroll) ->
// runtime-indexed array -> scratch (rule #20). Counters proved it: VGPR=128
// (not ~220), FETCH +1.8GB (scratch traffic), VALUBusy 13.5%, 6252us.
// Fix: full static unroll of the er_r init; all ta_r/er_r accesses are now
// compile-time-indexed. Expect VGPR ~200-240, FETCH -> ~0.5GB, k_scan ~1.6ms.

typedef unsigned short u16;
typedef unsigned int u32;
typedef short bf16x8_t __attribute__((ext_vector_type(8)));
typedef float f32x4_t __attribute__((ext_vector_type(4)));

#define NBLK 256
#define LOG2E 1.4426950408889634f
#define FP32_PAT 0x3F800000u

__device__ __forceinline__ float bf2f(u16 h) {
  return __builtin_bit_cast(float, (u32)h << 16);
}
__device__ __forceinline__ u16 f2bf(float f) {
  u32 u = __builtin_bit_cast(u32, f);
  return (u16)((u + 0x7fffu + ((u >> 16) & 1u)) >> 16);
}
__device__ __forceinline__ void bf8_to_f32(uint4 v, float* o) {
  o[0] = __builtin_bit_cast(float, v.x << 16);
  o[1] = __builtin_bit_cast(float, v.x & 0xffff0000u);
  o[2] = __builtin_bit_cast(float, v.y << 16);
  o[3] = __builtin_bit_cast(float, v.y & 0xffff0000u);
  o[4] = __builtin_bit_cast(float, v.z << 16);
  o[5] = __builtin_bit_cast(float, v.z & 0xffff0000u);
  o[6] = __builtin_bit_cast(float, v.w << 16);
  o[7] = __builtin_bit_cast(float, v.w & 0xffff0000u);
}
__device__ __forceinline__ float sigm(float x) {
  float e = __builtin_amdgcn_exp2f(x * -LOG2E);
  return __builtin_amdgcn_rcpf(1.f + e);
}
__device__ __forceinline__ float tanh_(float x) {
  float e = __builtin_amdgcn_exp2f(x * (2.f * LOG2E));
  return 1.f - 2.f * __builtin_amdgcn_rcpf(e + 1.f);
}
__device__ __forceinline__ bool probe_f32(const void* xm) {
  return *(const u32*)xm == FP32_PAT;
}

// Coherent (agent-scope, L2-bypassing) load/store for cross-block data.
__device__ __forceinline__ void gstore(float* p, float v) {
  __hip_atomic_store((u32*)p, __builtin_bit_cast(u32, v),
                     __ATOMIC_RELAXED, __HIP_MEMORY_SCOPE_AGENT);
}
__device__ __forceinline__ float gload(const float* p) {
  u32 u = __hip_atomic_load((const u32*)p, __ATOMIC_RELAXED,
                            __HIP_MEMORY_SCOPE_AGENT);
  return __builtin_bit_cast(float, u);
}

// Distributed-flag grid barrier, NO cache-flushing fences. slots[blk*32]
// holds block blk's epoch (128B stride). Thread i (<256) spins on slot i.
__device__ __forceinline__ void gbar2(u32* slots, u32 ep) {
  __syncthreads();  // compiler emits s_waitcnt vmcnt(0) before s_barrier:
                    // all this block's sc1 comm stores are acked first
  if (threadIdx.x == 0)
    __hip_atomic_store(slots + (size_t)blockIdx.x * 32, ep,
                       __ATOMIC_RELAXED, __HIP_MEMORY_SCOPE_AGENT);
  if (threadIdx.x < 256) {
    const u32* s = slots + (size_t)threadIdx.x * 32;
    while (__hip_atomic_load(s, __ATOMIC_RELAXED, __HIP_MEMORY_SCOPE_AGENT) < ep)
      __builtin_amdgcn_s_sleep(2);
  }
  __syncthreads();
}

// ---------------- k_convert ----------------
#define NSEG 19
struct Segs {
  const void* src[NSEG];
  u16* dst[NSEG];
  int n[NSEG];
};
__global__ void k_convert(Segs S, const u32* __restrict__ probe) {
  if (*probe != FP32_PAT) return;
  int seg = blockIdx.y;
  const float* src = (const float*)S.src[seg];
  u16* dst = S.dst[seg];
  int n = S.n[seg];
  for (int i = blockIdx.x * 256 + threadIdx.x; i < n; i += gridDim.x * 256)
    dst[i] = f2bf(src[i]);
}

// ---------------- k_atth: Ta = tanh(eout @ w_w.T + w_b) ----------------
__global__ __launch_bounds__(256) void k_atth(
    const void* __restrict__ eout_o, const u16* __restrict__ eoutB,
    const void* __restrict__ w_w_o, const u16* __restrict__ w_wB,
    const void* __restrict__ w_b_o, const u16* __restrict__ w_bB,
    u16* __restrict__ Ta, const u32* __restrict__ probe) {
  bool f32 = (*probe == FP32_PAT);
  const u16* eout = f32 ? eoutB : (const u16*)eout_o;
  const u16* w_w = f32 ? w_wB : (const u16*)w_w_o;
  const u16* w_b = f32 ? w_bB : (const u16*)w_b_o;
  int wave = threadIdx.x >> 6, lane = threadIdx.x & 63;
  int lm = lane & 15, lk8 = (lane >> 4) * 8;
  int m0 = blockIdx.x * 64 + wave * 16;
  int n0 = blockIdx.y * 64;
  f32x4_t acc[4] = {{0,0,0,0},{0,0,0,0},{0,0,0,0},{0,0,0,0}};
  const u16* arow = eout + (size_t)(m0 + lm) * 256 + lk8;
  for (int k0 = 0; k0 < 256; k0 += 32) {
    bf16x8_t af = *(const bf16x8_t*)(arow + k0);
#pragma unroll
    for (int nt = 0; nt < 4; ++nt) {
      const u16* brow = w_w + (size_t)(n0 + nt * 16 + lm) * 256 + k0 + lk8;
      bf16x8_t bf = *(const bf16x8_t*)brow;
      acc[nt] = __builtin_amdgcn_mfma_f32_16x16x32_bf16(af, bf, acc[nt], 0, 0, 0);
    }
  }
  int rb = (lane >> 4) * 4;
#pragma unroll
  for (int nt = 0; nt < 4; ++nt) {
    int n = n0 + nt * 16 + lm;
    float bias = bf2f(w_b[n]);
#pragma unroll
    for (int r2 = 0; r2 < 4; ++r2) {
      int m = m0 + rb + r2;
      Ta[(size_t)m * 256 + n] = f2bf(tanh_(acc[nt][r2] + bias));
    }
  }
}

// ---------------- k_logit ----------------
__global__ __launch_bounds__(256) void k_logit(
    const u16* __restrict__ dout,
    const void* __restrict__ cls_w_o, const u16* __restrict__ cls_wB,
    const void* __restrict__ cls_b_o, const u16* __restrict__ cls_bB,
    void* __restrict__ outp, const u32* __restrict__ probe) {
  bool f32 = (*probe == FP32_PAT);
  const u16* cls_w = f32 ? cls_wB : (const u16*)cls_w_o;
  const u16* cls_b = f32 ? cls_bB : (const u16*)cls_b_o;
  int wave = threadIdx.x >> 6, lane = threadIdx.x & 63;
  int lm = lane & 15, lk8 = (lane >> 4) * 8;
  int m0 = blockIdx.x * 64 + wave * 16;
  int n0 = blockIdx.y * 64;
  f32x4_t acc[4] = {{0,0,0,0},{0,0,0,0},{0,0,0,0},{0,0,0,0}};
  const u16* arow = dout + (size_t)(m0 + lm) * 768 + lk8;
#pragma unroll 4
  for (int k0 = 0; k0 < 768; k0 += 32) {
    bf16x8_t af = *(const bf16x8_t*)(arow + k0);
#pragma unroll
    for (int nt = 0; nt < 4; ++nt) {
      int n = n0 + nt * 16 + lm;
      int bn = (n < 4233) ? n : 0;
      bf16x8_t bf = *(const bf16x8_t*)(cls_w + (size_t)bn * 768 + k0 + lk8);
      acc[nt] = __builtin_amdgcn_mfma_f32_16x16x32_bf16(af, bf, acc[nt], 0, 0, 0);
    }
  }
  int rb = (lane >> 4) * 4;
#pragma unroll
  for (int nt = 0; nt < 4; ++nt) {
    int n = n0 + nt * 16 + lm;
    if (n < 4233) {
      float bias = bf2f(cls_b[n]);
#pragma unroll
      for (int r2 = 0; r2 < 4; ++r2) {
        int m = m0 + rb + r2;
        float v = acc[nt][r2] + bias;
        if (f32) ((float*)outp)[(size_t)m * 4233 + n] = v;
        else     ((u16*)outp)[(size_t)m * 4233 + n] = f2bf(v);
      }
    }
  }
}

// ---------------- k_scan helpers ----------------
// 512 threads: r = tid&63 (64 gate-rows), kq = tid>>6 (8 K-chunks of
// 64 Wih + 32 Whh elems). Partials land in scr[r][b*8+kq].
__device__ __forceinline__ void p1_gemm(
    const u16* __restrict__ Wih, const u16* __restrict__ Whh,
    const float (*x_l)[512], const float (*h_l)[256],
    float (*scr)[65], int tid, int hug) {
  int r = tid & 63, kq = tid >> 6;
  int hu = hug * 16 + (r >> 2), gate = r & 3;
  int wrow = gate * 256 + hu;
  float acc[8] = {0, 0, 0, 0, 0, 0, 0, 0};
  const u16* wp = Wih + (size_t)wrow * 512 + kq * 64;
#pragma unroll 4
  for (int c = 0; c < 8; ++c) {
    float wf[8];
    bf8_to_f32(*(const uint4*)(wp + c * 8), wf);
#pragma unroll
    for (int b = 0; b < 8; ++b) {
      const float* xp = &x_l[b][kq * 64 + c * 8];
#pragma unroll
      for (int j = 0; j < 8; ++j) acc[b] += wf[j] * xp[j];
    }
  }
  const u16* wp2 = Whh + (size_t)wrow * 256 + kq * 32;
#pragma unroll 4
  for (int c = 0; c < 4; ++c) {
    float wf[8];
    bf8_to_f32(*(const uint4*)(wp2 + c * 8), wf);
#pragma unroll
    for (int b = 0; b < 8; ++b) {
      const float* xp = &h_l[b][kq * 32 + c * 8];
#pragma unroll
      for (int j = 0; j < 8; ++j) acc[b] += wf[j] * xp[j];
    }
  }
#pragma unroll
  for (int b = 0; b < 8; ++b) scr[r][b * 8 + kq] = acc[b];
  __syncthreads();
}

// ---------------- k_scan ----------------
__global__ __launch_bounds__(512, 2) void k_scan(
    const void* __restrict__ eout_o, const u16* __restrict__ eoutB,
    const void* __restrict__ x_mask_o, const u16* __restrict__ x_maskB,
    const int* __restrict__ y,
    const void* __restrict__ y_mask_o, const u16* __restrict__ y_maskB,
    const void* __restrict__ emb_o, const u16* __restrict__ embB,
    const void* __restrict__ v_b_o, const u16* __restrict__ v_bB,
    const void* __restrict__ v_w_o, const u16* __restrict__ v_wB,
    const void* __restrict__ wav_o, const u16* __restrict__ wavB,
    const void* __restrict__ WihA_o, const u16* __restrict__ WihAB,
    const void* __restrict__ WhhA_o, const u16* __restrict__ WhhAB,
    const void* __restrict__ bihA_o, const u16* __restrict__ bihAB,
    const void* __restrict__ bhhA_o, const u16* __restrict__ bhhAB,
    const void* __restrict__ WihD_o, const u16* __restrict__ WihDB,
    const void* __restrict__ WhhD_o, const u16* __restrict__ WhhDB,
    const void* __restrict__ bihD_o, const u16* __restrict__ bihDB,
    const void* __restrict__ bhhD_o, const u16* __restrict__ bhhDB,
    u32* slots, float* h_dec, float* h_att,
    float* ctx_part, const u16* __restrict__ Ta,
    u16* __restrict__ dout) {
  __shared__ float x_l[8][512];
  __shared__ float h_l[8][256];
  __shared__ float scr[64][65];
  __shared__ float sp[512];
  __shared__ float hs_l[256], ts_l[256], wv_l[256], p_l[256];
  __shared__ float red_l[4];
  __shared__ float inv_es[8];
  __shared__ float ym_s[8];

  const bool f32 = probe_f32(x_mask_o);
  const u16* eout   = f32 ? eoutB  : (const u16*)eout_o;
  const u16* x_mask = f32 ? x_maskB: (const u16*)x_mask_o;
  const u16* y_mask = f32 ? y_maskB: (const u16*)y_mask_o;
  const u16* emb    = f32 ? embB   : (const u16*)emb_o;
  const u16* v_b    = f32 ? v_bB   : (const u16*)v_b_o;
  const u16* v_w    = f32 ? v_wB   : (const u16*)v_w_o;
  const u16* wav    = f32 ? wavB   : (const u16*)wav_o;
  const u16* WihA   = f32 ? WihAB  : (const u16*)WihA_o;
  const u16* WhhA   = f32 ? WhhAB  : (const u16*)WhhA_o;
  const u16* bihA   = f32 ? bihAB  : (const u16*)bihA_o;
  const u16* bhhA   = f32 ? bhhAB  : (const u16*)bhhA_o;
  const u16* WihD   = f32 ? WihDB  : (const u16*)WihD_o;
  const u16* WhhD   = f32 ? WhhDB  : (const u16*)WhhD_o;
  const u16* bihD   = f32 ? bihDB  : (const u16*)bihD_o;
  const u16* bhhD   = f32 ? bhhDB  : (const u16*)bhhD_o;

  const int tid = threadIdx.x, blk = blockIdx.x;
  const int bg = blk >> 5, sub = blk & 31;
  const bool is_att = (sub < 16);
  const int hug = is_att ? sub : (sub - 16);
  const int b2 = blk >> 2, tc = blk & 3;
  const int pos = tid & 255, half = tid >> 8;

  if (tid < 256) wv_l[tid] = bf2f(wav[tid]);
  float c_att_reg = 0.f;
  float c_dec_reg = 0.f;

  // ---- step-invariant register pins (phase 2 working set) ----
  // All accesses below are FULLY unrolled -> compile-time indices -> VGPRs.
  // Ta row-slice: row (b2*1024 + tc*256 + pos), contiguous half [half*128..)
  uint4 ta_r[16];
  {
    const u16* ar = Ta + ((size_t)(b2 * 1024 + tc * 256 + pos)) * 256 + half * 128;
#pragma unroll
    for (int i = 0; i < 16; ++i) ta_r[i] = ((const uint4*)ar)[i];
  }
  // eout column-slice: d = pos, tt in [half*128, half*128+128), packed pairs
  u32 er_r[64];
  {
    const u16* er = eout + ((size_t)(b2 * 1024 + tc * 256 + half * 128)) * 256 + pos;
#pragma unroll
    for (int k = 0; k < 64; ++k) {  // FULL unroll: static er_r indices
      u32 lo = er[(size_t)(2 * k) * 256];
      u32 hi = er[(size_t)(2 * k + 1) * 256];
      er_r[k] = lo | (hi << 16);
    }
  }
  // per-thread invariants
  const float xm_r = (bf2f(x_mask[b2 * 1024 + tc * 256 + pos]) - 1.f) * 1e30f;
  const float vb_r = bf2f(v_b[pos]);

  for (int t = 0; t <= 99; ++t) {
    if (is_att) {
      // per-batch invariant: softmax denominator reciprocal
      if (tid < 8 && t > 0) {
        const float* cp = ctx_part + (size_t)(bg * 8 + tid) * 4 * 257;
        float es = gload(cp + 256) + gload(cp + 257 + 256) +
                   gload(cp + 2 * 257 + 256) + gload(cp + 3 * 257 + 256);
        inv_es[tid] = 1.f / fmaxf(es, 1e-30f);
      }
      __syncthreads();
      for (int i = tid; i < 2048; i += 512) {
        int b = i >> 8, d = i & 255;
        int bglob = bg * 8 + b;
        int yv = y[bglob * 100 + t];
        x_l[b][d] = bf2f(emb[(size_t)yv * 256 + d]);
        float cx = 0.f;
        if (t > 0) {
          const float* cp = ctx_part + (size_t)bglob * 4 * 257;
          float s0 = gload(cp + d) + gload(cp + 257 + d) +
                     gload(cp + 2 * 257 + d) + gload(cp + 3 * 257 + d);
          cx = s0 * inv_es[b];
        }
        x_l[b][256 + d] = cx;
        h_l[b][d] = gload(h_att + (t & 1) * 16384 + bglob * 256 + d);
      }
      __syncthreads();
      if (t >= 1 && tid < 128) {
        int b = tid >> 4, dl = tid & 15;
        int bglob = bg * 8 + b, u = t - 1;
        float ym = bf2f(y_mask[bglob * 100 + u + 1]);
        float ym2 = ym * ym;
        int hu = hug * 16 + dl;
        size_t orow = ((size_t)bglob * 99 + u) * 768;
        dout[orow + hu] = f2bf(h_l[b][hu] * ym2);
        dout[orow + 256 + hu] = f2bf(x_l[b][256 + hu] * ym2);
      }
      if (t < 99) {
        p1_gemm(WihA, WhhA, x_l, h_l, scr, tid, hug);
        if (tid < 128) {
          int b = tid >> 4, dl = tid & 15;
          int bglob = bg * 8 + b;
          float g4[4];
#pragma unroll
          for (int gate = 0; gate < 4; ++gate) {
            int r2 = dl * 4 + gate;
            int wrow2 = gate * 256 + hug * 16 + dl;
            float sg = bf2f(bihA[wrow2]) + bf2f(bhhA[wrow2]);
#pragma unroll
            for (int q = 0; q < 8; ++q) sg += scr[r2][b * 8 + q];
            g4[gate] = sg;
          }
          float ii = sigm(g4[0]), ff = sigm(g4[1]), gg = tanh_(g4[2]), oo = sigm(g4[3]);
          float cn = ff * c_att_reg + ii * gg;
          c_att_reg = cn;
          float hn = oo * tanh_(cn);
          gstore(h_att + ((t + 1) & 1) * 16384 + bglob * 256 + hug * 16 + dl, hn);
        }
      }
    } else {
      if (t >= 1) {
        int s = t - 1;
        if (tid < 8) {
          int bglob = bg * 8 + tid;
          const float* cp = ctx_part + (size_t)bglob * 4 * 257;
          float es = gload(cp + 256) + gload(cp + 257 + 256) +
                     gload(cp + 2 * 257 + 256) + gload(cp + 3 * 257 + 256);
          inv_es[tid] = 1.f / fmaxf(es, 1e-30f);
          ym_s[tid] = bf2f(y_mask[bglob * 100 + s + 1]);
        }
        __syncthreads();
        for (int i = tid; i < 2048; i += 512) {
          int b = i >> 8, d = i & 255;
          int bglob = bg * 8 + b;
          float ym = ym_s[b];
          const float* cp = ctx_part + (size_t)bglob * 4 * 257;
          float s0 = gload(cp + d) + gload(cp + 257 + d) +
                     gload(cp + 2 * 257 + d) + gload(cp + 3 * 257 + d);
          float cx = s0 * inv_es[b];
          x_l[b][d] = gload(h_att + (t & 1) * 16384 + bglob * 256 + d) * ym;
          x_l[b][256 + d] = cx * ym;
          h_l[b][d] = gload(h_dec + (s & 1) * 16384 + bglob * 256 + d);
        }
        __syncthreads();
        p1_gemm(WihD, WhhD, x_l, h_l, scr, tid, hug);
        if (tid < 128) {
          int b = tid >> 4, dl = tid & 15;
          int bglob = bg * 8 + b;
          float g4[4];
#pragma unroll
          for (int gate = 0; gate < 4; ++gate) {
            int r2 = dl * 4 + gate;
            int wrow2 = gate * 256 + hug * 16 + dl;
            float sg = bf2f(bihD[wrow2]) + bf2f(bhhD[wrow2]);
#pragma unroll
            for (int q = 0; q < 8; ++q) sg += scr[r2][b * 8 + q];
            g4[gate] = sg;
          }
          float ii = sigm(g4[0]), ff = sigm(g4[1]), gg = tanh_(g4[2]), oo = sigm(g4[3]);
          float cn = ff * c_dec_reg + ii * gg;
          c_dec_reg = cn;
          float hn = oo * tanh_(cn);
          int hu_g = hug * 16 + dl;
          gstore(h_dec + ((s + 1) & 1) * 16384 + bglob * 256 + hu_g, hn);
          float ym = ym_s[b];
          dout[((size_t)bglob * 99 + s) * 768 + 512 + hu_g] = f2bf(hn * ym);
        }
      }
    }
    if (t == 99) break;
    gbar2(slots, (u32)(2 * t + 1));

    // -------- phase 2: scores + softmax + context (all 256 blocks) --------
    {
      int b = b2;
      if (tid < 256)
        hs_l[tid] = gload(h_att + ((t + 1) & 1) * 16384 + b * 256 + tid);
      __syncthreads();
      {  // st partial: thread (n=pos, half) does 128 k's, v_w ROW-major
        const u16* row = v_w + (size_t)pos * 256 + half * 128;
        float st = 0.f;
#pragma unroll
        for (int i = 0; i < 16; ++i) {
          float wf[8];
          bf8_to_f32(((const uint4*)row)[i], wf);
#pragma unroll
          for (int j = 0; j < 8; ++j) st += wf[j] * hs_l[half * 128 + i * 8 + j];
        }
        sp[tid] = st;
      }
      __syncthreads();
      if (tid < 256)
        ts_l[tid] = tanh_(sp[tid] + sp[tid + 256] + vb_r);
      __syncthreads();
      {  // score partial from pinned Ta regs: thread (pos, half) does 128 d's
        float sacc = 0.f;
#pragma unroll
        for (int i = 0; i < 16; ++i) {
          float af[8];
          bf8_to_f32(ta_r[i], af);
#pragma unroll
          for (int j = 0; j < 8; ++j) {
            int d = half * 128 + i * 8 + j;
            float tsv = ts_l[d], ta = af[j];
            float u = tsv + ta;
            float v = fmaf(tsv, ta, 1.f);
            sacc = fmaf(wv_l[d] * u, __builtin_amdgcn_rcpf(fmaxf(v, 1e-6f)), sacc);
          }
        }
        sp[tid] = sacc;
      }
      __syncthreads();
      if (tid < 256) {
        float s = sp[tid] + sp[tid + 256] + xm_r;
        s = fminf(s, 80.f);
        float p = __builtin_amdgcn_exp2f(s * LOG2E);
        p_l[tid] = p;
        float wsum = p;
#pragma unroll
        for (int off = 32; off; off >>= 1) wsum += __shfl_down(wsum, off);
        if ((tid & 63) == 0) red_l[tid >> 6] = wsum;
      }
      __syncthreads();
      {  // ctx partial from pinned eout regs: thread (d=pos, half), 128 tt's
        float a0 = 0.f;
#pragma unroll
        for (int k = 0; k < 64; ++k) {
          u32 v = er_r[k];
          a0 = fmaf(p_l[half * 128 + 2 * k],
                    __builtin_bit_cast(float, v << 16), a0);
          a0 = fmaf(p_l[half * 128 + 2 * k + 1],
                    __builtin_bit_cast(float, v & 0xffff0000u), a0);
        }
        sp[tid] = a0;
      }
      __syncthreads();
      if (tid < 256) {
        float* cslot = ctx_part + (size_t)(b * 4 + tc) * 257;
        gstore(cslot + tid, sp[tid] + sp[tid + 256]);
        if (tid == 0)
          gstore(cslot + 256, red_l[0] + red_l[1] + red_l[2] + red_l[3]);
      }
    }
    gbar2(slots, (u32)(2 * t + 2));
  }
}

extern "C" void kernel_launch(void* const* d_in, const int* in_sizes, int n_in,
                              void* d_out, int out_size, void* d_ws, size_t ws_size,
                              hipStream_t stream) {
  (void)in_sizes; (void)n_in; (void)out_size; (void)ws_size;
  const void* eout    = d_in[0];
  const void* x_mask  = d_in[1];
  const int*  y       = (const int*)d_in[2];
  const void* y_mask  = d_in[3];
  const void* emb     = d_in[4];
  const void* w_w     = d_in[5];
  const void* w_b     = d_in[6];
  const void* v_w     = d_in[7];
  const void* v_b     = d_in[8];
  const void* w_att_v = d_in[9];
  const void* Wih_att = d_in[10];
  const void* Whh_att = d_in[11];
  const void* bih_att = d_in[12];
  const void* bhh_att = d_in[13];
  const void* Wih_dec = d_in[14];
  const void* Whh_dec = d_in[15];
  const void* bih_dec = d_in[16];
  const void* bhh_dec = d_in[17];
  const void* cls_w   = d_in[18];
  const void* cls_b   = d_in[19];
  const u32* probe = (const u32*)x_mask;

  // d_out scratch: Ta then eoutB (fp32 mode only). Dead before k_logit.
  u16* TaB   = (u16*)d_out;
  u16* eoutB = TaB + 16777216;

  // ws layout (bytes), total ~22.7 MB
  char* w = (char*)d_ws;
  u32*   slots    = (u32*)(w + 0);           // 32768, zeroed
  float* h_dec    = (float*)(w + 32768);     // 131072, zeroed
  float* h_att    = (float*)(w + 163840);    // 131072 (buf0 zeroed via ZB)
  const size_t ZB = 229376;                  // zeroes slots+h_dec+h_att buf0
  float* ctx_part = (float*)(w + 491520);    // 263168
  u16*   v_wB     = (u16*)(w + 754688);      // 131072 (bf16 copy, row-major)
  u16*   dout     = (u16*)(w + 885760);      // 9732096 -> 10617856
  u16*   embB     = (u16*)(w + 10617856);
  u16*   WihAB    = (u16*)(w + 12785152);
  u16*   WhhAB    = (u16*)(w + 13833728);
  u16*   WihDB    = (u16*)(w + 14358016);
  u16*   WhhDB    = (u16*)(w + 15406592);
  u16*   bihAB    = (u16*)(w + 15930880);
  u16*   bhhAB    = (u16*)(w + 15932928);
  u16*   bihDB    = (u16*)(w + 15934976);
  u16*   bhhDB    = (u16*)(w + 15937024);
  u16*   v_bB     = (u16*)(w + 15939072);
  u16*   wavB     = (u16*)(w + 15939584);
  u16*   w_wB     = (u16*)(w + 15940096);
  u16*   w_bB     = (u16*)(w + 16071168);
  u16*   x_maskB  = (u16*)(w + 16071680);
  u16*   y_maskB  = (u16*)(w + 16202752);
  u16*   cls_wB   = (u16*)(w + 16215552);
  u16*   cls_bB   = (u16*)(w + 22717440);

  Segs S;
  const void* srcs[NSEG] = {eout, emb, Wih_att, Whh_att, Wih_dec, Whh_dec,
                            bih_att, bhh_att, bih_dec, bhh_dec, v_b, w_att_v,
                            w_w, w_b, x_mask, y_mask, cls_w, cls_b, v_w};
  u16* dsts[NSEG] = {eoutB, embB, WihAB, WhhAB, WihDB, WhhDB,
                     bihAB, bhhAB, bihDB, bhhDB, v_bB, wavB,
                     w_wB, w_bB, x_maskB, y_maskB, cls_wB, cls_bB, v_wB};
  int ns[NSEG] = {16777216, 1083648, 524288, 262144, 524288, 262144,
                  1024, 1024, 1024, 1024, 256, 256,
                  65536, 256, 65536, 6400, 3250944, 4233, 65536};
  for (int i = 0; i < NSEG; ++i) { S.src[i] = srcs[i]; S.dst[i] = dsts[i]; S.n[i] = ns[i]; }

  hipMemsetAsync(d_ws, 0, ZB, stream);
  hipLaunchKernelGGL(k_convert, dim3(4096, NSEG), dim3(256), 0, stream, S, probe);
  hipLaunchKernelGGL(k_atth, dim3(1024, 4), dim3(256), 0, stream,
                     eout, eoutB, w_w, w_wB, w_b, w_bB, TaB, probe);
  hipLaunchKernelGGL(k_scan, dim3(NBLK), dim3(512), 0, stream,
                     eout, eoutB, x_mask, x_maskB, y, y_mask, y_maskB,
                     emb, embB, v_b, v_bB, v_w, v_wB, w_att_v, wavB,
                     Wih_att, WihAB, Whh_att, WhhAB, bih_att, bihAB, bhh_att, bhhAB,
                     Wih_dec, WihDB, Whh_dec, WhhDB, bih_dec, bihDB, bhh_dec, bhhDB,
                     slots, h_dec, h_att, ctx_part, TaB, dout);
  hipLaunchKernelGGL(k_logit, dim3(99, 67), dim3(256), 0, stream,
                     dout, cls_w, cls_wB, cls_b, cls_bB, d_out, probe);
}

// Round 4
// 9333.967 us; speedup vs baseline: 1.0002x; 1.0002x over previous
//
#include <hip/hip_runtime.h>

// LAS decoder, dtype-adaptive (fp32 or bf16 inputs, probed on device via
// x_mask[0] as u32: fp32 1.0f = 0x3F800000, bf16 pair = 0x3F803F80).
// Round 9: force the register budget for the step-invariant pins.
// R7/R8 post-mortem: VGPR_Count stuck at exactly 128 = the 4-waves/SIMD
// allocation for a 512-thread block. __launch_bounds__(512,2) only sets a
// MINIMUM waves/EU; the backend's occupancy heuristic still targeted 4
// waves/EU and spilled/rematerialized the 128 pinned regs every t-step
// (FETCH grew 3.7->5.5->7.1 GB across attempts). Fix: replace with
// __attribute__((amdgpu_waves_per_eu(2,2))) -- min=2 caps VGPR at 256,
// max=2 stops the scheduler from chasing 4-wave occupancy, so the ~220-reg
// live set (64 ta_r + 64 er_r + ~90 working) fits with NO spill. Occupancy
// is unchanged (grid=256=1 block/CU=2 waves/SIMD already).
// Tell: VGPR_Count must jump to ~200-250. If it stays 128, abandon
// compiler-cooperative pinning.

typedef unsigned short u16;
typedef unsigned int u32;
typedef short bf16x8_t __attribute__((ext_vector_type(8)));
typedef float f32x4_t __attribute__((ext_vector_type(4)));

#define NBLK 256
#define LOG2E 1.4426950408889634f
#define FP32_PAT 0x3F800000u

__device__ __forceinline__ float bf2f(u16 h) {
  return __builtin_bit_cast(float, (u32)h << 16);
}
__device__ __forceinline__ u16 f2bf(float f) {
  u32 u = __builtin_bit_cast(u32, f);
  return (u16)((u + 0x7fffu + ((u >> 16) & 1u)) >> 16);
}
__device__ __forceinline__ void bf8_to_f32(uint4 v, float* o) {
  o[0] = __builtin_bit_cast(float, v.x << 16);
  o[1] = __builtin_bit_cast(float, v.x & 0xffff0000u);
  o[2] = __builtin_bit_cast(float, v.y << 16);
  o[3] = __builtin_bit_cast(float, v.y & 0xffff0000u);
  o[4] = __builtin_bit_cast(float, v.z << 16);
  o[5] = __builtin_bit_cast(float, v.z & 0xffff0000u);
  o[6] = __builtin_bit_cast(float, v.w << 16);
  o[7] = __builtin_bit_cast(float, v.w & 0xffff0000u);
}
__device__ __forceinline__ float sigm(float x) {
  float e = __builtin_amdgcn_exp2f(x * -LOG2E);
  return __builtin_amdgcn_rcpf(1.f + e);
}
__device__ __forceinline__ float tanh_(float x) {
  float e = __builtin_amdgcn_exp2f(x * (2.f * LOG2E));
  return 1.f - 2.f * __builtin_amdgcn_rcpf(e + 1.f);
}
__device__ __forceinline__ bool probe_f32(const void* xm) {
  return *(const u32*)xm == FP32_PAT;
}

// Coherent (agent-scope, L2-bypassing) load/store for cross-block data.
__device__ __forceinline__ void gstore(float* p, float v) {
  __hip_atomic_store((u32*)p, __builtin_bit_cast(u32, v),
                     __ATOMIC_RELAXED, __HIP_MEMORY_SCOPE_AGENT);
}
__device__ __forceinline__ float gload(const float* p) {
  u32 u = __hip_atomic_load((const u32*)p, __ATOMIC_RELAXED,
                            __HIP_MEMORY_SCOPE_AGENT);
  return __builtin_bit_cast(float, u);
}

// Distributed-flag grid barrier, NO cache-flushing fences. slots[blk*32]
// holds block blk's epoch (128B stride). Thread i (<256) spins on slot i.
__device__ __forceinline__ void gbar2(u32* slots, u32 ep) {
  __syncthreads();  // compiler emits s_waitcnt vmcnt(0) before s_barrier:
                    // all this block's sc1 comm stores are acked first
  if (threadIdx.x == 0)
    __hip_atomic_store(slots + (size_t)blockIdx.x * 32, ep,
                       __ATOMIC_RELAXED, __HIP_MEMORY_SCOPE_AGENT);
  if (threadIdx.x < 256) {
    const u32* s = slots + (size_t)threadIdx.x * 32;
    while (__hip_atomic_load(s, __ATOMIC_RELAXED, __HIP_MEMORY_SCOPE_AGENT) < ep)
      __builtin_amdgcn_s_sleep(2);
  }
  __syncthreads();
}

// ---------------- k_convert ----------------
#define NSEG 19
struct Segs {
  const void* src[NSEG];
  u16* dst[NSEG];
  int n[NSEG];
};
__global__ void k_convert(Segs S, const u32* __restrict__ probe) {
  if (*probe != FP32_PAT) return;
  int seg = blockIdx.y;
  const float* src = (const float*)S.src[seg];
  u16* dst = S.dst[seg];
  int n = S.n[seg];
  for (int i = blockIdx.x * 256 + threadIdx.x; i < n; i += gridDim.x * 256)
    dst[i] = f2bf(src[i]);
}

// ---------------- k_atth: Ta = tanh(eout @ w_w.T + w_b) ----------------
__global__ __launch_bounds__(256) void k_atth(
    const void* __restrict__ eout_o, const u16* __restrict__ eoutB,
    const void* __restrict__ w_w_o, const u16* __restrict__ w_wB,
    const void* __restrict__ w_b_o, const u16* __restrict__ w_bB,
    u16* __restrict__ Ta, const u32* __restrict__ probe) {
  bool f32 = (*probe == FP32_PAT);
  const u16* eout = f32 ? eoutB : (const u16*)eout_o;
  const u16* w_w = f32 ? w_wB : (const u16*)w_w_o;
  const u16* w_b = f32 ? w_bB : (const u16*)w_b_o;
  int wave = threadIdx.x >> 6, lane = threadIdx.x & 63;
  int lm = lane & 15, lk8 = (lane >> 4) * 8;
  int m0 = blockIdx.x * 64 + wave * 16;
  int n0 = blockIdx.y * 64;
  f32x4_t acc[4] = {{0,0,0,0},{0,0,0,0},{0,0,0,0},{0,0,0,0}};
  const u16* arow = eout + (size_t)(m0 + lm) * 256 + lk8;
  for (int k0 = 0; k0 < 256; k0 += 32) {
    bf16x8_t af = *(const bf16x8_t*)(arow + k0);
#pragma unroll
    for (int nt = 0; nt < 4; ++nt) {
      const u16* brow = w_w + (size_t)(n0 + nt * 16 + lm) * 256 + k0 + lk8;
      bf16x8_t bf = *(const bf16x8_t*)brow;
      acc[nt] = __builtin_amdgcn_mfma_f32_16x16x32_bf16(af, bf, acc[nt], 0, 0, 0);
    }
  }
  int rb = (lane >> 4) * 4;
#pragma unroll
  for (int nt = 0; nt < 4; ++nt) {
    int n = n0 + nt * 16 + lm;
    float bias = bf2f(w_b[n]);
#pragma unroll
    for (int r2 = 0; r2 < 4; ++r2) {
      int m = m0 + rb + r2;
      Ta[(size_t)m * 256 + n] = f2bf(tanh_(acc[nt][r2] + bias));
    }
  }
}

// ---------------- k_logit ----------------
__global__ __launch_bounds__(256) void k_logit(
    const u16* __restrict__ dout,
    const void* __restrict__ cls_w_o, const u16* __restrict__ cls_wB,
    const void* __restrict__ cls_b_o, const u16* __restrict__ cls_bB,
    void* __restrict__ outp, const u32* __restrict__ probe) {
  bool f32 = (*probe == FP32_PAT);
  const u16* cls_w = f32 ? cls_wB : (const u16*)cls_w_o;
  const u16* cls_b = f32 ? cls_bB : (const u16*)cls_b_o;
  int wave = threadIdx.x >> 6, lane = threadIdx.x & 63;
  int lm = lane & 15, lk8 = (lane >> 4) * 8;
  int m0 = blockIdx.x * 64 + wave * 16;
  int n0 = blockIdx.y * 64;
  f32x4_t acc[4] = {{0,0,0,0},{0,0,0,0},{0,0,0,0},{0,0,0,0}};
  const u16* arow = dout + (size_t)(m0 + lm) * 768 + lk8;
#pragma unroll 4
  for (int k0 = 0; k0 < 768; k0 += 32) {
    bf16x8_t af = *(const bf16x8_t*)(arow + k0);
#pragma unroll
    for (int nt = 0; nt < 4; ++nt) {
      int n = n0 + nt * 16 + lm;
      int bn = (n < 4233) ? n : 0;
      bf16x8_t bf = *(const bf16x8_t*)(cls_w + (size_t)bn * 768 + k0 + lk8);
      acc[nt] = __builtin_amdgcn_mfma_f32_16x16x32_bf16(af, bf, acc[nt], 0, 0, 0);
    }
  }
  int rb = (lane >> 4) * 4;
#pragma unroll
  for (int nt = 0; nt < 4; ++nt) {
    int n = n0 + nt * 16 + lm;
    if (n < 4233) {
      float bias = bf2f(cls_b[n]);
#pragma unroll
      for (int r2 = 0; r2 < 4; ++r2) {
        int m = m0 + rb + r2;
        float v = acc[nt][r2] + bias;
        if (f32) ((float*)outp)[(size_t)m * 4233 + n] = v;
        else     ((u16*)outp)[(size_t)m * 4233 + n] = f2bf(v);
      }
    }
  }
}

// ---------------- k_scan helpers ----------------
// 512 threads: r = tid&63 (64 gate-rows), kq = tid>>6 (8 K-chunks of
// 64 Wih + 32 Whh elems). Partials land in scr[r][b*8+kq].
__device__ __forceinline__ void p1_gemm(
    const u16* __restrict__ Wih, const u16* __restrict__ Whh,
    const float (*x_l)[512], const float (*h_l)[256],
    float (*scr)[65], int tid, int hug) {
  int r = tid & 63, kq = tid >> 6;
  int hu = hug * 16 + (r >> 2), gate = r & 3;
  int wrow = gate * 256 + hu;
  float acc[8] = {0, 0, 0, 0, 0, 0, 0, 0};
  const u16* wp = Wih + (size_t)wrow * 512 + kq * 64;
#pragma unroll 4
  for (int c = 0; c < 8; ++c) {
    float wf[8];
    bf8_to_f32(*(const uint4*)(wp + c * 8), wf);
#pragma unroll
    for (int b = 0; b < 8; ++b) {
      const float* xp = &x_l[b][kq * 64 + c * 8];
#pragma unroll
      for (int j = 0; j < 8; ++j) acc[b] += wf[j] * xp[j];
    }
  }
  const u16* wp2 = Whh + (size_t)wrow * 256 + kq * 32;
#pragma unroll 4
  for (int c = 0; c < 4; ++c) {
    float wf[8];
    bf8_to_f32(*(const uint4*)(wp2 + c * 8), wf);
#pragma unroll
    for (int b = 0; b < 8; ++b) {
      const float* xp = &h_l[b][kq * 32 + c * 8];
#pragma unroll
      for (int j = 0; j < 8; ++j) acc[b] += wf[j] * xp[j];
    }
  }
#pragma unroll
  for (int b = 0; b < 8; ++b) scr[r][b * 8 + kq] = acc[b];
  __syncthreads();
}

// ---------------- k_scan ----------------
__global__ __launch_bounds__(512)
__attribute__((amdgpu_waves_per_eu(2, 2))) void k_scan(
    const void* __restrict__ eout_o, const u16* __restrict__ eoutB,
    const void* __restrict__ x_mask_o, const u16* __restrict__ x_maskB,
    const int* __restrict__ y,
    const void* __restrict__ y_mask_o, const u16* __restrict__ y_maskB,
    const void* __restrict__ emb_o, const u16* __restrict__ embB,
    const void* __restrict__ v_b_o, const u16* __restrict__ v_bB,
    const void* __restrict__ v_w_o, const u16* __restrict__ v_wB,
    const void* __restrict__ wav_o, const u16* __restrict__ wavB,
    const void* __restrict__ WihA_o, const u16* __restrict__ WihAB,
    const void* __restrict__ WhhA_o, const u16* __restrict__ WhhAB,
    const void* __restrict__ bihA_o, const u16* __restrict__ bihAB,
    const void* __restrict__ bhhA_o, const u16* __restrict__ bhhAB,
    const void* __restrict__ WihD_o, const u16* __restrict__ WihDB,
    const void* __restrict__ WhhD_o, const u16* __restrict__ WhhDB,
    const void* __restrict__ bihD_o, const u16* __restrict__ bihDB,
    const void* __restrict__ bhhD_o, const u16* __restrict__ bhhDB,
    u32* slots, float* h_dec, float* h_att,
    float* ctx_part, const u16* __restrict__ Ta,
    u16* __restrict__ dout) {
  __shared__ float x_l[8][512];
  __shared__ float h_l[8][256];
  __shared__ float scr[64][65];
  __shared__ float sp[512];
  __shared__ float hs_l[256], ts_l[256], wv_l[256], p_l[256];
  __shared__ float red_l[4];
  __shared__ float inv_es[8];
  __shared__ float ym_s[8];

  const bool f32 = probe_f32(x_mask_o);
  const u16* eout   = f32 ? eoutB  : (const u16*)eout_o;
  const u16* x_mask = f32 ? x_maskB: (const u16*)x_mask_o;
  const u16* y_mask = f32 ? y_maskB: (const u16*)y_mask_o;
  const u16* emb    = f32 ? embB   : (const u16*)emb_o;
  const u16* v_b    = f32 ? v_bB   : (const u16*)v_b_o;
  const u16* v_w    = f32 ? v_wB   : (const u16*)v_w_o;
  const u16* wav    = f32 ? wavB   : (const u16*)wav_o;
  const u16* WihA   = f32 ? WihAB  : (const u16*)WihA_o;
  const u16* WhhA   = f32 ? WhhAB  : (const u16*)WhhA_o;
  const u16* bihA   = f32 ? bihAB  : (const u16*)bihA_o;
  const u16* bhhA   = f32 ? bhhAB  : (const u16*)bhhA_o;
  const u16* WihD   = f32 ? WihDB  : (const u16*)WihD_o;
  const u16* WhhD   = f32 ? WhhDB  : (const u16*)WhhD_o;
  const u16* bihD   = f32 ? bihDB  : (const u16*)bihD_o;
  const u16* bhhD   = f32 ? bhhDB  : (const u16*)bhhD_o;

  const int tid = threadIdx.x, blk = blockIdx.x;
  const int bg = blk >> 5, sub = blk & 31;
  const bool is_att = (sub < 16);
  const int hug = is_att ? sub : (sub - 16);
  const int b2 = blk >> 2, tc = blk & 3;
  const int pos = tid & 255, half = tid >> 8;

  if (tid < 256) wv_l[tid] = bf2f(wav[tid]);
  float c_att_reg = 0.f;
  float c_dec_reg = 0.f;

  // ---- step-invariant register pins (phase 2 working set) ----
  // All accesses below are FULLY unrolled -> compile-time indices -> VGPRs.
  // Ta row-slice: row (b2*1024 + tc*256 + pos), contiguous half [half*128..)
  uint4 ta_r[16];
  {
    const u16* ar = Ta + ((size_t)(b2 * 1024 + tc * 256 + pos)) * 256 + half * 128;
#pragma unroll
    for (int i = 0; i < 16; ++i) ta_r[i] = ((const uint4*)ar)[i];
  }
  // eout column-slice: d = pos, tt in [half*128, half*128+128), packed pairs
  u32 er_r[64];
  {
    const u16* er = eout + ((size_t)(b2 * 1024 + tc * 256 + half * 128)) * 256 + pos;
#pragma unroll
    for (int k = 0; k < 64; ++k) {  // FULL unroll: static er_r indices
      u32 lo = er[(size_t)(2 * k) * 256];
      u32 hi = er[(size_t)(2 * k + 1) * 256];
      er_r[k] = lo | (hi << 16);
    }
  }
  // per-thread invariants
  const float xm_r = (bf2f(x_mask[b2 * 1024 + tc * 256 + pos]) - 1.f) * 1e30f;
  const float vb_r = bf2f(v_b[pos]);

  for (int t = 0; t <= 99; ++t) {
    if (is_att) {
      // per-batch invariant: softmax denominator reciprocal
      if (tid < 8 && t > 0) {
        const float* cp = ctx_part + (size_t)(bg * 8 + tid) * 4 * 257;
        float es = gload(cp + 256) + gload(cp + 257 + 256) +
                   gload(cp + 2 * 257 + 256) + gload(cp + 3 * 257 + 256);
        inv_es[tid] = 1.f / fmaxf(es, 1e-30f);
      }
      __syncthreads();
      for (int i = tid; i < 2048; i += 512) {
        int b = i >> 8, d = i & 255;
        int bglob = bg * 8 + b;
        int yv = y[bglob * 100 + t];
        x_l[b][d] = bf2f(emb[(size_t)yv * 256 + d]);
        float cx = 0.f;
        if (t > 0) {
          const float* cp = ctx_part + (size_t)bglob * 4 * 257;
          float s0 = gload(cp + d) + gload(cp + 257 + d) +
                     gload(cp + 2 * 257 + d) + gload(cp + 3 * 257 + d);
          cx = s0 * inv_es[b];
        }
        x_l[b][256 + d] = cx;
        h_l[b][d] = gload(h_att + (t & 1) * 16384 + bglob * 256 + d);
      }
      __syncthreads();
      if (t >= 1 && tid < 128) {
        int b = tid >> 4, dl = tid & 15;
        int bglob = bg * 8 + b, u = t - 1;
        float ym = bf2f(y_mask[bglob * 100 + u + 1]);
        float ym2 = ym * ym;
        int hu = hug * 16 + dl;
        size_t orow = ((size_t)bglob * 99 + u) * 768;
        dout[orow + hu] = f2bf(h_l[b][hu] * ym2);
        dout[orow + 256 + hu] = f2bf(x_l[b][256 + hu] * ym2);
      }
      if (t < 99) {
        p1_gemm(WihA, WhhA, x_l, h_l, scr, tid, hug);
        if (tid < 128) {
          int b = tid >> 4, dl = tid & 15;
          int bglob = bg * 8 + b;
          float g4[4];
#pragma unroll
          for (int gate = 0; gate < 4; ++gate) {
            int r2 = dl * 4 + gate;
            int wrow2 = gate * 256 + hug * 16 + dl;
            float sg = bf2f(bihA[wrow2]) + bf2f(bhhA[wrow2]);
#pragma unroll
            for (int q = 0; q < 8; ++q) sg += scr[r2][b * 8 + q];
            g4[gate] = sg;
          }
          float ii = sigm(g4[0]), ff = sigm(g4[1]), gg = tanh_(g4[2]), oo = sigm(g4[3]);
          float cn = ff * c_att_reg + ii * gg;
          c_att_reg = cn;
          float hn = oo * tanh_(cn);
          gstore(h_att + ((t + 1) & 1) * 16384 + bglob * 256 + hug * 16 + dl, hn);
        }
      }
    } else {
      if (t >= 1) {
        int s = t - 1;
        if (tid < 8) {
          int bglob = bg * 8 + tid;
          const float* cp = ctx_part + (size_t)bglob * 4 * 257;
          float es = gload(cp + 256) + gload(cp + 257 + 256) +
                     gload(cp + 2 * 257 + 256) + gload(cp + 3 * 257 + 256);
          inv_es[tid] = 1.f / fmaxf(es, 1e-30f);
          ym_s[tid] = bf2f(y_mask[bglob * 100 + s + 1]);
        }
        __syncthreads();
        for (int i = tid; i < 2048; i += 512) {
          int b = i >> 8, d = i & 255;
          int bglob = bg * 8 + b;
          float ym = ym_s[b];
          const float* cp = ctx_part + (size_t)bglob * 4 * 257;
          float s0 = gload(cp + d) + gload(cp + 257 + d) +
                     gload(cp + 2 * 257 + d) + gload(cp + 3 * 257 + d);
          float cx = s0 * inv_es[b];
          x_l[b][d] = gload(h_att + (t & 1) * 16384 + bglob * 256 + d) * ym;
          x_l[b][256 + d] = cx * ym;
          h_l[b][d] = gload(h_dec + (s & 1) * 16384 + bglob * 256 + d);
        }
        __syncthreads();
        p1_gemm(WihD, WhhD, x_l, h_l, scr, tid, hug);
        if (tid < 128) {
          int b = tid >> 4, dl = tid & 15;
          int bglob = bg * 8 + b;
          float g4[4];
#pragma unroll
          for (int gate = 0; gate < 4; ++gate) {
            int r2 = dl * 4 + gate;
            int wrow2 = gate * 256 + hug * 16 + dl;
            float sg = bf2f(bihD[wrow2]) + bf2f(bhhD[wrow2]);
#pragma unroll
            for (int q = 0; q < 8; ++q) sg += scr[r2][b * 8 + q];
            g4[gate] = sg;
          }
          float ii = sigm(g4[0]), ff = sigm(g4[1]), gg = tanh_(g4[2]), oo = sigm(g4[3]);
          float cn = ff * c_dec_reg + ii * gg;
          c_dec_reg = cn;
          float hn = oo * tanh_(cn);
          int hu_g = hug * 16 + dl;
          gstore(h_dec + ((s + 1) & 1) * 16384 + bglob * 256 + hu_g, hn);
          float ym = ym_s[b];
          dout[((size_t)bglob * 99 + s) * 768 + 512 + hu_g] = f2bf(hn * ym);
        }
      }
    }
    if (t == 99) break;
    gbar2(slots, (u32)(2 * t + 1));

    // -------- phase 2: scores + softmax + context (all 256 blocks) --------
    {
      int b = b2;
      if (tid < 256)
        hs_l[tid] = gload(h_att + ((t + 1) & 1) * 16384 + b * 256 + tid);
      __syncthreads();
      {  // st partial: thread (n=pos, half) does 128 k's, v_w ROW-major
        const u16* row = v_w + (size_t)pos * 256 + half * 128;
        float st = 0.f;
#pragma unroll
        for (int i = 0; i < 16; ++i) {
          float wf[8];
          bf8_to_f32(((const uint4*)row)[i], wf);
#pragma unroll
          for (int j = 0; j < 8; ++j) st += wf[j] * hs_l[half * 128 + i * 8 + j];
        }
        sp[tid] = st;
      }
      __syncthreads();
      if (tid < 256)
        ts_l[tid] = tanh_(sp[tid] + sp[tid + 256] + vb_r);
      __syncthreads();
      {  // score partial from pinned Ta regs: thread (pos, half) does 128 d's
        float sacc = 0.f;
#pragma unroll
        for (int i = 0; i < 16; ++i) {
          float af[8];
          bf8_to_f32(ta_r[i], af);
#pragma unroll
          for (int j = 0; j < 8; ++j) {
            int d = half * 128 + i * 8 + j;
            float tsv = ts_l[d], ta = af[j];
            float u = tsv + ta;
            float v = fmaf(tsv, ta, 1.f);
            sacc = fmaf(wv_l[d] * u, __builtin_amdgcn_rcpf(fmaxf(v, 1e-6f)), sacc);
          }
        }
        sp[tid] = sacc;
      }
      __syncthreads();
      if (tid < 256) {
        float s = sp[tid] + sp[tid + 256] + xm_r;
        s = fminf(s, 80.f);
        float p = __builtin_amdgcn_exp2f(s * LOG2E);
        p_l[tid] = p;
        float wsum = p;
#pragma unroll
        for (int off = 32; off; off >>= 1) wsum += __shfl_down(wsum, off);
        if ((tid & 63) == 0) red_l[tid >> 6] = wsum;
      }
      __syncthreads();
      {  // ctx partial from pinned eout regs: thread (d=pos, half), 128 tt's
        float a0 = 0.f;
#pragma unroll
        for (int k = 0; k < 64; ++k) {
          u32 v = er_r[k];
          a0 = fmaf(p_l[half * 128 + 2 * k],
                    __builtin_bit_cast(float, v << 16), a0);
          a0 = fmaf(p_l[half * 128 + 2 * k + 1],
                    __builtin_bit_cast(float, v & 0xffff0000u), a0);
        }
        sp[tid] = a0;
      }
      __syncthreads();
      if (tid < 256) {
        float* cslot = ctx_part + (size_t)(b * 4 + tc) * 257;
        gstore(cslot + tid, sp[tid] + sp[tid + 256]);
        if (tid == 0)
          gstore(cslot + 256, red_l[0] + red_l[1] + red_l[2] + red_l[3]);
      }
    }
    gbar2(slots, (u32)(2 * t + 2));
  }
}

extern "C" void kernel_launch(void* const* d_in, const int* in_sizes, int n_in,
                              void* d_out, int out_size, void* d_ws, size_t ws_size,
                              hipStream_t stream) {
  (void)in_sizes; (void)n_in; (void)out_size; (void)ws_size;
  const void* eout    = d_in[0];
  const void* x_mask  = d_in[1];
  const int*  y       = (const int*)d_in[2];
  const void* y_mask  = d_in[3];
  const void* emb     = d_in[4];
  const void* w_w     = d_in[5];
  const void* w_b     = d_in[6];
  const void* v_w     = d_in[7];
  const void* v_b     = d_in[8];
  const void* w_att_v = d_in[9];
  const void* Wih_att = d_in[10];
  const void* Whh_att = d_in[11];
  const void* bih_att = d_in[12];
  const void* bhh_att = d_in[13];
  const void* Wih_dec = d_in[14];
  const void* Whh_dec = d_in[15];
  const void* bih_dec = d_in[16];
  const void* bhh_dec = d_in[17];
  const void* cls_w   = d_in[18];
  const void* cls_b   = d_in[19];
  const u32* probe = (const u32*)x_mask;

  // d_out scratch: Ta then eoutB (fp32 mode only). Dead before k_logit.
  u16* TaB   = (u16*)d_out;
  u16* eoutB = TaB + 16777216;

  // ws layout (bytes), total ~22.7 MB
  char* w = (char*)d_ws;
  u32*   slots    = (u32*)(w + 0);           // 32768, zeroed
  float* h_dec    = (float*)(w + 32768);     // 131072, zeroed
  float* h_att    = (float*)(w + 163840);    // 131072 (buf0 zeroed via ZB)
  const size_t ZB = 229376;                  // zeroes slots+h_dec+h_att buf0
  float* ctx_part = (float*)(w + 491520);    // 263168
  u16*   v_wB     = (u16*)(w + 754688);      // 131072 (bf16 copy, row-major)
  u16*   dout     = (u16*)(w + 885760);      // 9732096 -> 10617856
  u16*   embB     = (u16*)(w + 10617856);
  u16*   WihAB    = (u16*)(w + 12785152);
  u16*   WhhAB    = (u16*)(w + 13833728);
  u16*   WihDB    = (u16*)(w + 14358016);
  u16*   WhhDB    = (u16*)(w + 15406592);
  u16*   bihAB    = (u16*)(w + 15930880);
  u16*   bhhAB    = (u16*)(w + 15932928);
  u16*   bihDB    = (u16*)(w + 15934976);
  u16*   bhhDB    = (u16*)(w + 15937024);
  u16*   v_bB     = (u16*)(w + 15939072);
  u16*   wavB     = (u16*)(w + 15939584);
  u16*   w_wB     = (u16*)(w + 15940096);
  u16*   w_bB     = (u16*)(w + 16071168);
  u16*   x_maskB  = (u16*)(w + 16071680);
  u16*   y_maskB  = (u16*)(w + 16202752);
  u16*   cls_wB   = (u16*)(w + 16215552);
  u16*   cls_bB   = (u16*)(w + 22717440);

  Segs S;
  const void* srcs[NSEG] = {eout, emb, Wih_att, Whh_att, Wih_dec, Whh_dec,
                            bih_att, bhh_att, bih_dec, bhh_dec, v_b, w_att_v,
                            w_w, w_b, x_mask, y_mask, cls_w, cls_b, v_w};
  u16* dsts[NSEG] = {eoutB, embB, WihAB, WhhAB, WihDB, WhhDB,
                     bihAB, bhhAB, bihDB, bhhDB, v_bB, wavB,
                     w_wB, w_bB, x_maskB, y_maskB, cls_wB, cls_bB, v_wB};
  int ns[NSEG] = {16777216, 1083648, 524288, 262144, 524288, 262144,
                  1024, 1024, 1024, 1024, 256, 256,
                  65536, 256, 65536, 6400, 3250944, 4233, 65536};
  for (int i = 0; i < NSEG; ++i) { S.src[i] = srcs[i]; S.dst[i] = dsts[i]; S.n[i] = ns[i]; }

  hipMemsetAsync(d_ws, 0, ZB, stream);
  hipLaunchKernelGGL(k_convert, dim3(4096, NSEG), dim3(256), 0, stream, S, probe);
  hipLaunchKernelGGL(k_atth, dim3(1024, 4), dim3(256), 0, stream,
                     eout, eoutB, w_w, w_wB, w_b, w_bB, TaB, probe);
  hipLaunchKernelGGL(k_scan, dim3(NBLK), dim3(512), 0, stream,
                     eout, eoutB, x_mask, x_maskB, y, y_mask, y_maskB,
                     emb, embB, v_b, v_bB, v_w, v_wB, w_att_v, wavB,
                     Wih_att, WihAB, Whh_att, WhhAB, bih_att, bihAB, bhh_att, bhhAB,
                     Wih_dec, WihDB, Whh_dec, WhhDB, bih_dec, bihDB, bhh_dec, bhhDB,
                     slots, h_dec, h_att, ctx_part, TaB, dout);
  hipLaunchKernelGGL(k_logit, dim3(99, 67), dim3(256), 0, stream,
                     dout, cls_w, cls_wB, cls_b, cls_bB, d_out, probe);
}

// Round 5
// 6546.777 us; speedup vs baseline: 1.4260x; 1.4257x over previous
//
#include <hip/hip_runtime.h>

// LAS decoder, dtype-adaptive (fp32 or bf16 inputs, probed on device via
// x_mask[0] as u32: fp32 1.0f = 0x3F800000, bf16 pair = 0x3F803F80).
// Round 10: LDS-pin the Ta slice. R7-R9 tried to pin step-invariant slices
// in VGPRs; the backend held VGPR_Count at 128 (4-wave/EU budget) through
// full unrolls and amdgpu_waves_per_eu(2,2), spilling every attempt ->
// abandoned per R9 pre-commitment. The slice CAN live in LDS: 160KB/CU.
// Layout (exactly 163840 B):
//   [0      ) Ta slice, 128KB, XOR-swizzled (chunk c ^= row&15; linear
//             512B row stride would be a 32-way bank conflict, G4)
//   [131072 ) x_l f32[8][512] 16KB  -- phase-2 scratch overlaid here
//   [147456 ) h_l f32[8][256] 8KB
//   [155648 ) scr f32[64*32] 8KB    -- two-stage (+4-wave add) reduction,
//             rotation-swizzled (s+r)&31; inv_es/ym_s alias scr head
// eout ctx loop streams from global again: with Ta out of L2, per-XCD L2
// working set (32 blocks x 128KB eout + weights) ~= 4MB -> L2-hot.
// scr compaction: waves kq<4 write slot b*4+kq, sync, kq>=4 add into
// b*4+(kq-4); gate-sum reads 4 slots. wv_l reloaded per step (overlay),
// dec-epilogue ym re-loaded directly from y_mask.

typedef unsigned short u16;
typedef unsigned int u32;
typedef short bf16x8_t __attribute__((ext_vector_type(8)));
typedef float f32x4_t __attribute__((ext_vector_type(4)));

#define NBLK 256
#define LOG2E 1.4426950408889634f
#define FP32_PAT 0x3F800000u

__device__ __forceinline__ float bf2f(u16 h) {
  return __builtin_bit_cast(float, (u32)h << 16);
}
__device__ __forceinline__ u16 f2bf(float f) {
  u32 u = __builtin_bit_cast(u32, f);
  return (u16)((u + 0x7fffu + ((u >> 16) & 1u)) >> 16);
}
__device__ __forceinline__ void bf8_to_f32(uint4 v, float* o) {
  o[0] = __builtin_bit_cast(float, v.x << 16);
  o[1] = __builtin_bit_cast(float, v.x & 0xffff0000u);
  o[2] = __builtin_bit_cast(float, v.y << 16);
  o[3] = __builtin_bit_cast(float, v.y & 0xffff0000u);
  o[4] = __builtin_bit_cast(float, v.z << 16);
  o[5] = __builtin_bit_cast(float, v.z & 0xffff0000u);
  o[6] = __builtin_bit_cast(float, v.w << 16);
  o[7] = __builtin_bit_cast(float, v.w & 0xffff0000u);
}
__device__ __forceinline__ float sigm(float x) {
  float e = __builtin_amdgcn_exp2f(x * -LOG2E);
  return __builtin_amdgcn_rcpf(1.f + e);
}
__device__ __forceinline__ float tanh_(float x) {
  float e = __builtin_amdgcn_exp2f(x * (2.f * LOG2E));
  return 1.f - 2.f * __builtin_amdgcn_rcpf(e + 1.f);
}
__device__ __forceinline__ bool probe_f32(const void* xm) {
  return *(const u32*)xm == FP32_PAT;
}

// Coherent (agent-scope, L2-bypassing) load/store for cross-block data.
__device__ __forceinline__ void gstore(float* p, float v) {
  __hip_atomic_store((u32*)p, __builtin_bit_cast(u32, v),
                     __ATOMIC_RELAXED, __HIP_MEMORY_SCOPE_AGENT);
}
__device__ __forceinline__ float gload(const float* p) {
  u32 u = __hip_atomic_load((const u32*)p, __ATOMIC_RELAXED,
                            __HIP_MEMORY_SCOPE_AGENT);
  return __builtin_bit_cast(float, u);
}

// Distributed-flag grid barrier, NO cache-flushing fences. slots[blk*32]
// holds block blk's epoch (128B stride). Thread i (<256) spins on slot i.
__device__ __forceinline__ void gbar2(u32* slots, u32 ep) {
  __syncthreads();  // compiler emits s_waitcnt vmcnt(0) before s_barrier:
                    // all this block's sc1 comm stores are acked first
  if (threadIdx.x == 0)
    __hip_atomic_store(slots + (size_t)blockIdx.x * 32, ep,
                       __ATOMIC_RELAXED, __HIP_MEMORY_SCOPE_AGENT);
  if (threadIdx.x < 256) {
    const u32* s = slots + (size_t)threadIdx.x * 32;
    while (__hip_atomic_load(s, __ATOMIC_RELAXED, __HIP_MEMORY_SCOPE_AGENT) < ep)
      __builtin_amdgcn_s_sleep(2);
  }
  __syncthreads();
}

// ---------------- k_convert ----------------
#define NSEG 19
struct Segs {
  const void* src[NSEG];
  u16* dst[NSEG];
  int n[NSEG];
};
__global__ void k_convert(Segs S, const u32* __restrict__ probe) {
  if (*probe != FP32_PAT) return;
  int seg = blockIdx.y;
  const float* src = (const float*)S.src[seg];
  u16* dst = S.dst[seg];
  int n = S.n[seg];
  for (int i = blockIdx.x * 256 + threadIdx.x; i < n; i += gridDim.x * 256)
    dst[i] = f2bf(src[i]);
}

// ---------------- k_atth: Ta = tanh(eout @ w_w.T + w_b) ----------------
__global__ __launch_bounds__(256) void k_atth(
    const void* __restrict__ eout_o, const u16* __restrict__ eoutB,
    const void* __restrict__ w_w_o, const u16* __restrict__ w_wB,
    const void* __restrict__ w_b_o, const u16* __restrict__ w_bB,
    u16* __restrict__ Ta, const u32* __restrict__ probe) {
  bool f32 = (*probe == FP32_PAT);
  const u16* eout = f32 ? eoutB : (const u16*)eout_o;
  const u16* w_w = f32 ? w_wB : (const u16*)w_w_o;
  const u16* w_b = f32 ? w_bB : (const u16*)w_b_o;
  int wave = threadIdx.x >> 6, lane = threadIdx.x & 63;
  int lm = lane & 15, lk8 = (lane >> 4) * 8;
  int m0 = blockIdx.x * 64 + wave * 16;
  int n0 = blockIdx.y * 64;
  f32x4_t acc[4] = {{0,0,0,0},{0,0,0,0},{0,0,0,0},{0,0,0,0}};
  const u16* arow = eout + (size_t)(m0 + lm) * 256 + lk8;
  for (int k0 = 0; k0 < 256; k0 += 32) {
    bf16x8_t af = *(const bf16x8_t*)(arow + k0);
#pragma unroll
    for (int nt = 0; nt < 4; ++nt) {
      const u16* brow = w_w + (size_t)(n0 + nt * 16 + lm) * 256 + k0 + lk8;
      bf16x8_t bf = *(const bf16x8_t*)brow;
      acc[nt] = __builtin_amdgcn_mfma_f32_16x16x32_bf16(af, bf, acc[nt], 0, 0, 0);
    }
  }
  int rb = (lane >> 4) * 4;
#pragma unroll
  for (int nt = 0; nt < 4; ++nt) {
    int n = n0 + nt * 16 + lm;
    float bias = bf2f(w_b[n]);
#pragma unroll
    for (int r2 = 0; r2 < 4; ++r2) {
      int m = m0 + rb + r2;
      Ta[(size_t)m * 256 + n] = f2bf(tanh_(acc[nt][r2] + bias));
    }
  }
}

// ---------------- k_logit ----------------
__global__ __launch_bounds__(256) void k_logit(
    const u16* __restrict__ dout,
    const void* __restrict__ cls_w_o, const u16* __restrict__ cls_wB,
    const void* __restrict__ cls_b_o, const u16* __restrict__ cls_bB,
    void* __restrict__ outp, const u32* __restrict__ probe) {
  bool f32 = (*probe == FP32_PAT);
  const u16* cls_w = f32 ? cls_wB : (const u16*)cls_w_o;
  const u16* cls_b = f32 ? cls_bB : (const u16*)cls_b_o;
  int wave = threadIdx.x >> 6, lane = threadIdx.x & 63;
  int lm = lane & 15, lk8 = (lane >> 4) * 8;
  int m0 = blockIdx.x * 64 + wave * 16;
  int n0 = blockIdx.y * 64;
  f32x4_t acc[4] = {{0,0,0,0},{0,0,0,0},{0,0,0,0},{0,0,0,0}};
  const u16* arow = dout + (size_t)(m0 + lm) * 768 + lk8;
#pragma unroll 4
  for (int k0 = 0; k0 < 768; k0 += 32) {
    bf16x8_t af = *(const bf16x8_t*)(arow + k0);
#pragma unroll
    for (int nt = 0; nt < 4; ++nt) {
      int n = n0 + nt * 16 + lm;
      int bn = (n < 4233) ? n : 0;
      bf16x8_t bf = *(const bf16x8_t*)(cls_w + (size_t)bn * 768 + k0 + lk8);
      acc[nt] = __builtin_amdgcn_mfma_f32_16x16x32_bf16(af, bf, acc[nt], 0, 0, 0);
    }
  }
  int rb = (lane >> 4) * 4;
#pragma unroll
  for (int nt = 0; nt < 4; ++nt) {
    int n = n0 + nt * 16 + lm;
    if (n < 4233) {
      float bias = bf2f(cls_b[n]);
#pragma unroll
      for (int r2 = 0; r2 < 4; ++r2) {
        int m = m0 + rb + r2;
        float v = acc[nt][r2] + bias;
        if (f32) ((float*)outp)[(size_t)m * 4233 + n] = v;
        else     ((u16*)outp)[(size_t)m * 4233 + n] = f2bf(v);
      }
    }
  }
}

// ---------------- k_scan helpers ----------------
// 512 threads: r = tid&63 (64 gate-rows), kq = tid>>6 (8 K-chunks).
// Two-stage reduction into scr[64][32] (rotation-swizzled): waves kq<4
// write slot b*4+kq; sync; waves kq>=4 ADD into slot b*4+(kq-4); sync.
__device__ __forceinline__ void p1_gemm(
    const u16* __restrict__ Wih, const u16* __restrict__ Whh,
    const float (*x_l)[512], const float (*h_l)[256],
    float* scr, int tid, int hug) {
  int r = tid & 63, kq = tid >> 6;
  int hu = hug * 16 + (r >> 2), gate = r & 3;
  int wrow = gate * 256 + hu;
  float acc[8] = {0, 0, 0, 0, 0, 0, 0, 0};
  const u16* wp = Wih + (size_t)wrow * 512 + kq * 64;
#pragma unroll 4
  for (int c = 0; c < 8; ++c) {
    float wf[8];
    bf8_to_f32(*(const uint4*)(wp + c * 8), wf);
#pragma unroll
    for (int b = 0; b < 8; ++b) {
      const float* xp = &x_l[b][kq * 64 + c * 8];
#pragma unroll
      for (int j = 0; j < 8; ++j) acc[b] += wf[j] * xp[j];
    }
  }
  const u16* wp2 = Whh + (size_t)wrow * 256 + kq * 32;
#pragma unroll 4
  for (int c = 0; c < 4; ++c) {
    float wf[8];
    bf8_to_f32(*(const uint4*)(wp2 + c * 8), wf);
#pragma unroll
    for (int b = 0; b < 8; ++b) {
      const float* xp = &h_l[b][kq * 32 + c * 8];
#pragma unroll
      for (int j = 0; j < 8; ++j) acc[b] += wf[j] * xp[j];
    }
  }
  int slot = kq & 3;
  if (kq < 4) {
#pragma unroll
    for (int b = 0; b < 8; ++b)
      scr[r * 32 + ((b * 4 + slot + r) & 31)] = acc[b];
  }
  __syncthreads();
  if (kq >= 4) {
#pragma unroll
    for (int b = 0; b < 8; ++b) {
      int idx = r * 32 + ((b * 4 + slot + r) & 31);
      scr[idx] += acc[b];
    }
  }
  __syncthreads();
}

// ---------------- k_scan ----------------
__global__ __launch_bounds__(512) void k_scan(
    const void* __restrict__ eout_o, const u16* __restrict__ eoutB,
    const void* __restrict__ x_mask_o, const u16* __restrict__ x_maskB,
    const int* __restrict__ y,
    const void* __restrict__ y_mask_o, const u16* __restrict__ y_maskB,
    const void* __restrict__ emb_o, const u16* __restrict__ embB,
    const void* __restrict__ v_b_o, const u16* __restrict__ v_bB,
    const void* __restrict__ v_w_o, const u16* __restrict__ v_wB,
    const void* __restrict__ wav_o, const u16* __restrict__ wavB,
    const void* __restrict__ WihA_o, const u16* __restrict__ WihAB,
    const void* __restrict__ WhhA_o, const u16* __restrict__ WhhAB,
    const void* __restrict__ bihA_o, const u16* __restrict__ bihAB,
    const void* __restrict__ bhhA_o, const u16* __restrict__ bhhAB,
    const void* __restrict__ WihD_o, const u16* __restrict__ WihDB,
    const void* __restrict__ WhhD_o, const u16* __restrict__ WhhDB,
    const void* __restrict__ bihD_o, const u16* __restrict__ bihDB,
    const void* __restrict__ bhhD_o, const u16* __restrict__ bhhDB,
    u32* slots, float* h_dec, float* h_att,
    float* ctx_part, const u16* __restrict__ Ta,
    u16* __restrict__ dout) {
  // 160 KiB LDS, exact budget. See header comment for the map.
  __shared__ __align__(16) unsigned char smem[163840];
  float (*x_l)[512] = (float (*)[512])(smem + 131072);
  float (*h_l)[256] = (float (*)[256])(smem + 147456);
  float* scr    = (float*)(smem + 155648);
  float* inv_es = scr;          // alive only before gemm clobbers scr
  float* ym_s   = scr + 8;
  float* sp     = (float*)(smem + 131072);           // overlay in x_l
  float* hs_l   = (float*)(smem + 131072 + 2048);
  float* ts_l   = (float*)(smem + 131072 + 3072);
  float* p_l    = (float*)(smem + 131072 + 4096);
  float* wv_l   = (float*)(smem + 131072 + 5120);
  float* red_l  = (float*)(smem + 131072 + 6144);

  const bool f32 = probe_f32(x_mask_o);
  const u16* eout   = f32 ? eoutB  : (const u16*)eout_o;
  const u16* x_mask = f32 ? x_maskB: (const u16*)x_mask_o;
  const u16* y_mask = f32 ? y_maskB: (const u16*)y_mask_o;
  const u16* emb    = f32 ? embB   : (const u16*)emb_o;
  const u16* v_b    = f32 ? v_bB   : (const u16*)v_b_o;
  const u16* v_w    = f32 ? v_wB   : (const u16*)v_w_o;
  const u16* wav    = f32 ? wavB   : (const u16*)wav_o;
  const u16* WihA   = f32 ? WihAB  : (const u16*)WihA_o;
  const u16* WhhA   = f32 ? WhhAB  : (const u16*)WhhA_o;
  const u16* bihA   = f32 ? bihAB  : (const u16*)bihA_o;
  const u16* bhhA   = f32 ? bhhAB  : (const u16*)bhhA_o;
  const u16* WihD   = f32 ? WihDB  : (const u16*)WihD_o;
  const u16* WhhD   = f32 ? WhhDB  : (const u16*)WhhD_o;
  const u16* bihD   = f32 ? bihDB  : (const u16*)bihD_o;
  const u16* bhhD   = f32 ? bhhDB  : (const u16*)bhhD_o;

  const int tid = threadIdx.x, blk = blockIdx.x;
  const int bg = blk >> 5, sub = blk & 31;
  const bool is_att = (sub < 16);
  const int hug = is_att ? sub : (sub - 16);
  const int b2 = blk >> 2, tc = blk & 3;
  const int pos = tid & 255, half = tid >> 8;

  float c_att_reg = 0.f;
  float c_dec_reg = 0.f;

  // per-thread step invariants
  const float xm_r = (bf2f(x_mask[b2 * 1024 + tc * 256 + pos]) - 1.f) * 1e30f;
  const float vb_r = bf2f(v_b[pos]);

  // ---- stage this block's Ta slice (256 rows x 256 d, bf16) into LDS ----
  // Swizzle: 16B chunk c of row goes to c' = c ^ (row & 15). Linear layout
  // would put every row's chunk c in the same banks (512B stride, G4).
  {
    const u16* src = Ta + (size_t)(b2 * 1024 + tc * 256) * 256;
#pragma unroll
    for (int k = 0; k < 16; ++k) {
      int g = k * 512 + tid;            // 8192 chunks of 16B
      int row = g >> 5, c = g & 31;
      int cp = c ^ (row & 15);
      *(uint4*)(smem + row * 512 + cp * 16) = ((const uint4*)src)[g];
    }
  }
  __syncthreads();

  for (int t = 0; t <= 99; ++t) {
    if (is_att) {
      // per-batch invariant: softmax denominator reciprocal
      if (tid < 8 && t > 0) {
        const float* cp = ctx_part + (size_t)(bg * 8 + tid) * 4 * 257;
        float es = gload(cp + 256) + gload(cp + 257 + 256) +
                   gload(cp + 2 * 257 + 256) + gload(cp + 3 * 257 + 256);
        inv_es[tid] = 1.f / fmaxf(es, 1e-30f);
      }
      __syncthreads();
      for (int i = tid; i < 2048; i += 512) {
        int b = i >> 8, d = i & 255;
        int bglob = bg * 8 + b;
        int yv = y[bglob * 100 + t];
        x_l[b][d] = bf2f(emb[(size_t)yv * 256 + d]);
        float cx = 0.f;
        if (t > 0) {
          const float* cp = ctx_part + (size_t)bglob * 4 * 257;
          float s0 = gload(cp + d) + gload(cp + 257 + d) +
                     gload(cp + 2 * 257 + d) + gload(cp + 3 * 257 + d);
          cx = s0 * inv_es[b];
        }
        x_l[b][256 + d] = cx;
        h_l[b][d] = gload(h_att + (t & 1) * 16384 + bglob * 256 + d);
      }
      __syncthreads();
      if (t >= 1 && tid < 128) {
        int b = tid >> 4, dl = tid & 15;
        int bglob = bg * 8 + b, u = t - 1;
        float ym = bf2f(y_mask[bglob * 100 + u + 1]);
        float ym2 = ym * ym;
        int hu = hug * 16 + dl;
        size_t orow = ((size_t)bglob * 99 + u) * 768;
        dout[orow + hu] = f2bf(h_l[b][hu] * ym2);
        dout[orow + 256 + hu] = f2bf(x_l[b][256 + hu] * ym2);
      }
      if (t < 99) {
        p1_gemm(WihA, WhhA, x_l, h_l, scr, tid, hug);
        if (tid < 128) {
          int b = tid >> 4, dl = tid & 15;
          int bglob = bg * 8 + b;
          float g4[4];
#pragma unroll
          for (int gate = 0; gate < 4; ++gate) {
            int r2 = dl * 4 + gate;
            int wrow2 = gate * 256 + hug * 16 + dl;
            float sg = bf2f(bihA[wrow2]) + bf2f(bhhA[wrow2]);
#pragma unroll
            for (int q = 0; q < 4; ++q)
              sg += scr[r2 * 32 + ((b * 4 + q + r2) & 31)];
            g4[gate] = sg;
          }
          float ii = sigm(g4[0]), ff = sigm(g4[1]), gg = tanh_(g4[2]), oo = sigm(g4[3]);
          float cn = ff * c_att_reg + ii * gg;
          c_att_reg = cn;
          float hn = oo * tanh_(cn);
          gstore(h_att + ((t + 1) & 1) * 16384 + bglob * 256 + hug * 16 + dl, hn);
        }
      }
    } else {
      if (t >= 1) {
        int s = t - 1;
        if (tid < 8) {
          int bglob = bg * 8 + tid;
          const float* cp = ctx_part + (size_t)bglob * 4 * 257;
          float es = gload(cp + 256) + gload(cp + 257 + 256) +
                     gload(cp + 2 * 257 + 256) + gload(cp + 3 * 257 + 256);
          inv_es[tid] = 1.f / fmaxf(es, 1e-30f);
          ym_s[tid] = bf2f(y_mask[bglob * 100 + s + 1]);
        }
        __syncthreads();
        for (int i = tid; i < 2048; i += 512) {
          int b = i >> 8, d = i & 255;
          int bglob = bg * 8 + b;
          float ym = ym_s[b];
          const float* cp = ctx_part + (size_t)bglob * 4 * 257;
          float s0 = gload(cp + d) + gload(cp + 257 + d) +
                     gload(cp + 2 * 257 + d) + gload(cp + 3 * 257 + d);
          float cx = s0 * inv_es[b];
          x_l[b][d] = gload(h_att + (t & 1) * 16384 + bglob * 256 + d) * ym;
          x_l[b][256 + d] = cx * ym;
          h_l[b][d] = gload(h_dec + (s & 1) * 16384 + bglob * 256 + d);
        }
        __syncthreads();
        p1_gemm(WihD, WhhD, x_l, h_l, scr, tid, hug);
        if (tid < 128) {
          int b = tid >> 4, dl = tid & 15;
          int bglob = bg * 8 + b;
          float g4[4];
#pragma unroll
          for (int gate = 0; gate < 4; ++gate) {
            int r2 = dl * 4 + gate;
            int wrow2 = gate * 256 + hug * 16 + dl;
            float sg = bf2f(bihD[wrow2]) + bf2f(bhhD[wrow2]);
#pragma unroll
            for (int q = 0; q < 4; ++q)
              sg += scr[r2 * 32 + ((b * 4 + q + r2) & 31)];
            g4[gate] = sg;
          }
          float ii = sigm(g4[0]), ff = sigm(g4[1]), gg = tanh_(g4[2]), oo = sigm(g4[3]);
          float cn = ff * c_dec_reg + ii * gg;
          c_dec_reg = cn;
          float hn = oo * tanh_(cn);
          int hu_g = hug * 16 + dl;
          gstore(h_dec + ((s + 1) & 1) * 16384 + bglob * 256 + hu_g, hn);
          float ym = bf2f(y_mask[bglob * 100 + s + 1]);  // ym_s clobbered by scr
          dout[((size_t)bglob * 99 + s) * 768 + 512 + hu_g] = f2bf(hn * ym);
        }
      }
    }
    if (t == 99) break;
    gbar2(slots, (u32)(2 * t + 1));

    // -------- phase 2: scores + softmax + context (all 256 blocks) --------
    {
      int b = b2;
      if (tid < 256) {
        hs_l[tid] = gload(h_att + ((t + 1) & 1) * 16384 + b * 256 + tid);
        wv_l[tid] = bf2f(wav[tid]);   // overlay clobbered each step
      }
      __syncthreads();
      {  // st partial: thread (n=pos, half) does 128 k's, v_w ROW-major
        const u16* row = v_w + (size_t)pos * 256 + half * 128;
        float st = 0.f;
#pragma unroll
        for (int i = 0; i < 16; ++i) {
          float wf[8];
          bf8_to_f32(((const uint4*)row)[i], wf);
#pragma unroll
          for (int j = 0; j < 8; ++j) st += wf[j] * hs_l[half * 128 + i * 8 + j];
        }
        sp[tid] = st;
      }
      __syncthreads();
      if (tid < 256)
        ts_l[tid] = tanh_(sp[tid] + sp[tid + 256] + vb_r);
      __syncthreads();
      {  // score partial from LDS Ta (swizzled): thread (pos, half), 128 d's
        float sacc = 0.f;
        const unsigned char* tarow = smem + pos * 512;
#pragma unroll
        for (int i = 0; i < 16; ++i) {
          int c = half * 16 + i;
          int cp = c ^ (pos & 15);
          float af[8];
          bf8_to_f32(*(const uint4*)(tarow + cp * 16), af);
#pragma unroll
          for (int j = 0; j < 8; ++j) {
            int d = half * 128 + i * 8 + j;
            float tsv = ts_l[d], ta = af[j];
            float u = tsv + ta;
            float v = fmaf(tsv, ta, 1.f);
            sacc = fmaf(wv_l[d] * u, __builtin_amdgcn_rcpf(fmaxf(v, 1e-6f)), sacc);
          }
        }
        sp[tid] = sacc;
      }
      __syncthreads();
      if (tid < 256) {
        float s = sp[tid] + sp[tid + 256] + xm_r;
        s = fminf(s, 80.f);
        float p = __builtin_amdgcn_exp2f(s * LOG2E);
        p_l[tid] = p;
        float wsum = p;
#pragma unroll
        for (int off = 32; off; off >>= 1) wsum += __shfl_down(wsum, off);
        if ((tid & 63) == 0) red_l[tid >> 6] = wsum;
      }
      __syncthreads();
      {  // ctx partial streaming eout from global (L2-hot now Ta is in LDS)
        const u16* er = eout + ((size_t)(b * 1024 + tc * 256 + half * 128)) * 256 + pos;
        float a0 = 0.f;
#pragma unroll 16
        for (int tt = 0; tt < 128; ++tt)
          a0 += p_l[half * 128 + tt] * bf2f(er[(size_t)tt * 256]);
        sp[tid] = a0;
      }
      __syncthreads();
      if (tid < 256) {
        float* cslot = ctx_part + (size_t)(b * 4 + tc) * 257;
        gstore(cslot + tid, sp[tid] + sp[tid + 256]);
        if (tid == 0)
          gstore(cslot + 256, red_l[0] + red_l[1] + red_l[2] + red_l[3]);
      }
    }
    gbar2(slots, (u32)(2 * t + 2));
  }
}

extern "C" void kernel_launch(void* const* d_in, const int* in_sizes, int n_in,
                              void* d_out, int out_size, void* d_ws, size_t ws_size,
                              hipStream_t stream) {
  (void)in_sizes; (void)n_in; (void)out_size; (void)ws_size;
  const void* eout    = d_in[0];
  const void* x_mask  = d_in[1];
  const int*  y       = (const int*)d_in[2];
  const void* y_mask  = d_in[3];
  const void* emb     = d_in[4];
  const void* w_w     = d_in[5];
  const void* w_b     = d_in[6];
  const void* v_w     = d_in[7];
  const void* v_b     = d_in[8];
  const void* w_att_v = d_in[9];
  const void* Wih_att = d_in[10];
  const void* Whh_att = d_in[11];
  const void* bih_att = d_in[12];
  const void* bhh_att = d_in[13];
  const void* Wih_dec = d_in[14];
  const void* Whh_dec = d_in[15];
  const void* bih_dec = d_in[16];
  const void* bhh_dec = d_in[17];
  const void* cls_w   = d_in[18];
  const void* cls_b   = d_in[19];
  const u32* probe = (const u32*)x_mask;

  // d_out scratch: Ta then eoutB (fp32 mode only). Dead before k_logit.
  u16* TaB   = (u16*)d_out;
  u16* eoutB = TaB + 16777216;

  // ws layout (bytes), total ~22.7 MB
  char* w = (char*)d_ws;
  u32*   slots    = (u32*)(w + 0);           // 32768, zeroed
  float* h_dec    = (float*)(w + 32768);     // 131072, zeroed
  float* h_att    = (float*)(w + 163840);    // 131072 (buf0 zeroed via ZB)
  const size_t ZB = 229376;                  // zeroes slots+h_dec+h_att buf0
  float* ctx_part = (float*)(w + 491520);    // 263168
  u16*   v_wB     = (u16*)(w + 754688);      // 131072 (bf16 copy, row-major)
  u16*   dout     = (u16*)(w + 885760);      // 9732096 -> 10617856
  u16*   embB     = (u16*)(w + 10617856);
  u16*   WihAB    = (u16*)(w + 12785152);
  u16*   WhhAB    = (u16*)(w + 13833728);
  u16*   WihDB    = (u16*)(w + 14358016);
  u16*   WhhDB    = (u16*)(w + 15406592);
  u16*   bihAB    = (u16*)(w + 15930880);
  u16*   bhhAB    = (u16*)(w + 15932928);
  u16*   bihDB    = (u16*)(w + 15934976);
  u16*   bhhDB    = (u16*)(w + 15937024);
  u16*   v_bB     = (u16*)(w + 15939072);
  u16*   wavB     = (u16*)(w + 15939584);
  u16*   w_wB     = (u16*)(w + 15940096);
  u16*   w_bB     = (u16*)(w + 16071168);
  u16*   x_maskB  = (u16*)(w + 16071680);
  u16*   y_maskB  = (u16*)(w + 16202752);
  u16*   cls_wB   = (u16*)(w + 16215552);
  u16*   cls_bB   = (u16*)(w + 22717440);

  Segs S;
  const void* srcs[NSEG] = {eout, emb, Wih_att, Whh_att, Wih_dec, Whh_dec,
                            bih_att, bhh_att, bih_dec, bhh_dec, v_b, w_att_v,
                            w_w, w_b, x_mask, y_mask, cls_w, cls_b, v_w};
  u16* dsts[NSEG] = {eoutB, embB, WihAB, WhhAB, WihDB, WhhDB,
                     bihAB, bhhAB, bihDB, bhhDB, v_bB, wavB,
                     w_wB, w_bB, x_maskB, y_maskB, cls_wB, cls_bB, v_wB};
  int ns[NSEG] = {16777216, 1083648, 524288, 262144, 524288, 262144,
                  1024, 1024, 1024, 1024, 256, 256,
                  65536, 256, 65536, 6400, 3250944, 4233, 65536};
  for (int i = 0; i < NSEG; ++i) { S.src[i] = srcs[i]; S.dst[i] = dsts[i]; S.n[i] = ns[i]; }

  hipMemsetAsync(d_ws, 0, ZB, stream);
  hipLaunchKernelGGL(k_convert, dim3(4096, NSEG), dim3(256), 0, stream, S, probe);
  hipLaunchKernelGGL(k_atth, dim3(1024, 4), dim3(256), 0, stream,
                     eout, eoutB, w_w, w_wB, w_b, w_bB, TaB, probe);
  hipLaunchKernelGGL(k_scan, dim3(NBLK), dim3(512), 0, stream,
                     eout, eoutB, x_mask, x_maskB, y, y_mask, y_maskB,
                     emb, embB, v_b, v_bB, v_w, v_wB, w_att_v, wavB,
                     Wih_att, WihAB, Whh_att, WhhAB, bih_att, bihAB, bhh_att, bhhAB,
                     Wih_dec, WihDB, Whh_dec, WhhDB, bih_dec, bihDB, bhh_dec, bhhDB,
                     slots, h_dec, h_att, ctx_part, TaB, dout);
  hipLaunchKernelGGL(k_logit, dim3(99, 67), dim3(256), 0, stream,
                     dout, cls_w, cls_wB, cls_b, cls_bB, d_out, probe);
}

// Round 7
// 3212.788 us; speedup vs baseline: 2.9057x; 2.0377x over previous
//
#include <hip/hip_runtime.h>

// LAS decoder, dtype-adaptive (fp32 or bf16 inputs, probed on device via
// x_mask[0] as u32: fp32 1.0f = 0x3F800000, bf16 pair = 0x3F803F80).
// Round 12 = Round 11 resubmitted verbatim (R11 bench died in the broker:
// "MI355X container failed twice" -- no kernel verdict. Audit found no
// hang path: barrier epochs uniform across blocks, LDS=163840B already
// proven in R10, overlay lifetimes barrier-separated.)
// R11 theory: LDS-pin the EOUT slice (not Ta). R10 pinned Ta but left the
// ctx loop's eout column-walk in global; it lost all L2 residency (FETCH
// 2.79GB = exactly the eout stream) and its miss latency serialized phase 2
// (5985us, VALUBusy 16%). eout is the array consumed COLUMN-wise -> it is
// the one that belongs in LDS; Ta is consumed row-per-thread (16 uint4,
// proven fast from global in R6's 3200us). Also: back to separately-NAMED
// __shared__ arrays (R10 used one 160KB char blob + casts, which defeats
// LDS alias analysis; R6's gemm codegen context is restored).
// LDS = eout_l 128K + x_l 16K + h_l 8K + scr 8K = 163840 exactly.
// ctx consume from LDS: lanes read consecutive u16 -> 2-lane/dword
// broadcast, conflict-free, no swizzle needed. scr uses R10's verified
// two-stage rotation-swizzled reduction (budget forces 8KB). Phase-2
// scratch overlays x_l (cast, barrier-separated); wv_l reloaded per step;
// inv_es/ym_s alias scr head; dec-epilogue ym reloads from y_mask.

typedef unsigned short u16;
typedef unsigned int u32;
typedef short bf16x8_t __attribute__((ext_vector_type(8)));
typedef float f32x4_t __attribute__((ext_vector_type(4)));

#define NBLK 256
#define LOG2E 1.4426950408889634f
#define FP32_PAT 0x3F800000u

__device__ __forceinline__ float bf2f(u16 h) {
  return __builtin_bit_cast(float, (u32)h << 16);
}
__device__ __forceinline__ u16 f2bf(float f) {
  u32 u = __builtin_bit_cast(u32, f);
  return (u16)((u + 0x7fffu + ((u >> 16) & 1u)) >> 16);
}
__device__ __forceinline__ void bf8_to_f32(uint4 v, float* o) {
  o[0] = __builtin_bit_cast(float, v.x << 16);
  o[1] = __builtin_bit_cast(float, v.x & 0xffff0000u);
  o[2] = __builtin_bit_cast(float, v.y << 16);
  o[3] = __builtin_bit_cast(float, v.y & 0xffff0000u);
  o[4] = __builtin_bit_cast(float, v.z << 16);
  o[5] = __builtin_bit_cast(float, v.z & 0xffff0000u);
  o[6] = __builtin_bit_cast(float, v.w << 16);
  o[7] = __builtin_bit_cast(float, v.w & 0xffff0000u);
}
__device__ __forceinline__ float sigm(float x) {
  float e = __builtin_amdgcn_exp2f(x * -LOG2E);
  return __builtin_amdgcn_rcpf(1.f + e);
}
__device__ __forceinline__ float tanh_(float x) {
  float e = __builtin_amdgcn_exp2f(x * (2.f * LOG2E));
  return 1.f - 2.f * __builtin_amdgcn_rcpf(e + 1.f);
}
__device__ __forceinline__ bool probe_f32(const void* xm) {
  return *(const u32*)xm == FP32_PAT;
}

// Coherent (agent-scope, L2-bypassing) load/store for cross-block data.
__device__ __forceinline__ void gstore(float* p, float v) {
  __hip_atomic_store((u32*)p, __builtin_bit_cast(u32, v),
                     __ATOMIC_RELAXED, __HIP_MEMORY_SCOPE_AGENT);
}
__device__ __forceinline__ float gload(const float* p) {
  u32 u = __hip_atomic_load((const u32*)p, __ATOMIC_RELAXED,
                            __HIP_MEMORY_SCOPE_AGENT);
  return __builtin_bit_cast(float, u);
}

// Distributed-flag grid barrier, NO cache-flushing fences. slots[blk*32]
// holds block blk's epoch (128B stride). Thread i (<256) spins on slot i.
__device__ __forceinline__ void gbar2(u32* slots, u32 ep) {
  __syncthreads();  // compiler emits s_waitcnt vmcnt(0) before s_barrier:
                    // all this block's sc1 comm stores are acked first
  if (threadIdx.x == 0)
    __hip_atomic_store(slots + (size_t)blockIdx.x * 32, ep,
                       __ATOMIC_RELAXED, __HIP_MEMORY_SCOPE_AGENT);
  if (threadIdx.x < 256) {
    const u32* s = slots + (size_t)threadIdx.x * 32;
    while (__hip_atomic_load(s, __ATOMIC_RELAXED, __HIP_MEMORY_SCOPE_AGENT) < ep)
      __builtin_amdgcn_s_sleep(2);
  }
  __syncthreads();
}

// ---------------- k_convert ----------------
#define NSEG 18
struct Segs {
  const void* src[NSEG];
  u16* dst[NSEG];
  int n[NSEG];
};
__global__ void k_convert(Segs S, const u32* __restrict__ probe) {
  if (*probe != FP32_PAT) return;
  int seg = blockIdx.y;
  const float* src = (const float*)S.src[seg];
  u16* dst = S.dst[seg];
  int n = S.n[seg];
  for (int i = blockIdx.x * 256 + threadIdx.x; i < n; i += gridDim.x * 256)
    dst[i] = f2bf(src[i]);
}

// ---------------- k_vwt ----------------
__global__ void k_vwt(const void* __restrict__ v_w, u16* __restrict__ vwT,
                      const u32* __restrict__ probe) {
  bool f32 = (*probe == FP32_PAT);
  int idx = blockIdx.x * 256 + threadIdx.x;  // 65536
  int k = idx >> 8, d = idx & 255;
  vwT[idx] = f32 ? f2bf(((const float*)v_w)[d * 256 + k])
                 : ((const u16*)v_w)[d * 256 + k];
}

// ---------------- k_atth: Ta = tanh(eout @ w_w.T + w_b) ----------------
__global__ __launch_bounds__(256) void k_atth(
    const void* __restrict__ eout_o, const u16* __restrict__ eoutB,
    const void* __restrict__ w_w_o, const u16* __restrict__ w_wB,
    const void* __restrict__ w_b_o, const u16* __restrict__ w_bB,
    u16* __restrict__ Ta, const u32* __restrict__ probe) {
  bool f32 = (*probe == FP32_PAT);
  const u16* eout = f32 ? eoutB : (const u16*)eout_o;
  const u16* w_w = f32 ? w_wB : (const u16*)w_w_o;
  const u16* w_b = f32 ? w_bB : (const u16*)w_b_o;
  int wave = threadIdx.x >> 6, lane = threadIdx.x & 63;
  int lm = lane & 15, lk8 = (lane >> 4) * 8;
  int m0 = blockIdx.x * 64 + wave * 16;
  int n0 = blockIdx.y * 64;
  f32x4_t acc[4] = {{0,0,0,0},{0,0,0,0},{0,0,0,0},{0,0,0,0}};
  const u16* arow = eout + (size_t)(m0 + lm) * 256 + lk8;
  for (int k0 = 0; k0 < 256; k0 += 32) {
    bf16x8_t af = *(const bf16x8_t*)(arow + k0);
#pragma unroll
    for (int nt = 0; nt < 4; ++nt) {
      const u16* brow = w_w + (size_t)(n0 + nt * 16 + lm) * 256 + k0 + lk8;
      bf16x8_t bf = *(const bf16x8_t*)brow;
      acc[nt] = __builtin_amdgcn_mfma_f32_16x16x32_bf16(af, bf, acc[nt], 0, 0, 0);
    }
  }
  int rb = (lane >> 4) * 4;
#pragma unroll
  for (int nt = 0; nt < 4; ++nt) {
    int n = n0 + nt * 16 + lm;
    float bias = bf2f(w_b[n]);
#pragma unroll
    for (int r2 = 0; r2 < 4; ++r2) {
      int m = m0 + rb + r2;
      Ta[(size_t)m * 256 + n] = f2bf(tanh_(acc[nt][r2] + bias));
    }
  }
}

// ---------------- k_logit ----------------
__global__ __launch_bounds__(256) void k_logit(
    const u16* __restrict__ dout,
    const void* __restrict__ cls_w_o, const u16* __restrict__ cls_wB,
    const void* __restrict__ cls_b_o, const u16* __restrict__ cls_bB,
    void* __restrict__ outp, const u32* __restrict__ probe) {
  bool f32 = (*probe == FP32_PAT);
  const u16* cls_w = f32 ? cls_wB : (const u16*)cls_w_o;
  const u16* cls_b = f32 ? cls_bB : (const u16*)cls_b_o;
  int wave = threadIdx.x >> 6, lane = threadIdx.x & 63;
  int lm = lane & 15, lk8 = (lane >> 4) * 8;
  int m0 = blockIdx.x * 64 + wave * 16;
  int n0 = blockIdx.y * 64;
  f32x4_t acc[4] = {{0,0,0,0},{0,0,0,0},{0,0,0,0},{0,0,0,0}};
  const u16* arow = dout + (size_t)(m0 + lm) * 768 + lk8;
#pragma unroll 4
  for (int k0 = 0; k0 < 768; k0 += 32) {
    bf16x8_t af = *(const bf16x8_t*)(arow + k0);
#pragma unroll
    for (int nt = 0; nt < 4; ++nt) {
      int n = n0 + nt * 16 + lm;
      int bn = (n < 4233) ? n : 0;
      bf16x8_t bf = *(const bf16x8_t*)(cls_w + (size_t)bn * 768 + k0 + lk8);
      acc[nt] = __builtin_amdgcn_mfma_f32_16x16x32_bf16(af, bf, acc[nt], 0, 0, 0);
    }
  }
  int rb = (lane >> 4) * 4;
#pragma unroll
  for (int nt = 0; nt < 4; ++nt) {
    int n = n0 + nt * 16 + lm;
    if (n < 4233) {
      float bias = bf2f(cls_b[n]);
#pragma unroll
      for (int r2 = 0; r2 < 4; ++r2) {
        int m = m0 + rb + r2;
        float v = acc[nt][r2] + bias;
        if (f32) ((float*)outp)[(size_t)m * 4233 + n] = v;
        else     ((u16*)outp)[(size_t)m * 4233 + n] = f2bf(v);
      }
    }
  }
}

// ---------------- k_scan helpers ----------------
// 512 threads: r = tid&63 (64 gate-rows), kq = tid>>6 (8 K-chunks).
// Two-stage reduction into scr[64*32] (rotation-swizzled): waves kq<4
// write slot b*4+kq; sync; waves kq>=4 ADD into slot b*4+(kq-4); sync.
__device__ __forceinline__ void p1_gemm(
    const u16* __restrict__ Wih, const u16* __restrict__ Whh,
    const float (*x_l)[512], const float (*h_l)[256],
    float* scr, int tid, int hug) {
  int r = tid & 63, kq = tid >> 6;
  int hu = hug * 16 + (r >> 2), gate = r & 3;
  int wrow = gate * 256 + hu;
  float acc[8] = {0, 0, 0, 0, 0, 0, 0, 0};
  const u16* wp = Wih + (size_t)wrow * 512 + kq * 64;
#pragma unroll 4
  for (int c = 0; c < 8; ++c) {
    float wf[8];
    bf8_to_f32(*(const uint4*)(wp + c * 8), wf);
#pragma unroll
    for (int b = 0; b < 8; ++b) {
      const float* xp = &x_l[b][kq * 64 + c * 8];
#pragma unroll
      for (int j = 0; j < 8; ++j) acc[b] += wf[j] * xp[j];
    }
  }
  const u16* wp2 = Whh + (size_t)wrow * 256 + kq * 32;
#pragma unroll 4
  for (int c = 0; c < 4; ++c) {
    float wf[8];
    bf8_to_f32(*(const uint4*)(wp2 + c * 8), wf);
#pragma unroll
    for (int b = 0; b < 8; ++b) {
      const float* xp = &h_l[b][kq * 32 + c * 8];
#pragma unroll
      for (int j = 0; j < 8; ++j) acc[b] += wf[j] * xp[j];
    }
  }
  int slot = kq & 3;
  if (kq < 4) {
#pragma unroll
    for (int b = 0; b < 8; ++b)
      scr[r * 32 + ((b * 4 + slot + r) & 31)] = acc[b];
  }
  __syncthreads();
  if (kq >= 4) {
#pragma unroll
    for (int b = 0; b < 8; ++b) {
      int idx = r * 32 + ((b * 4 + slot + r) & 31);
      scr[idx] += acc[b];
    }
  }
  __syncthreads();
}

// ---------------- k_scan ----------------
__global__ __launch_bounds__(512) void k_scan(
    const void* __restrict__ eout_o, const u16* __restrict__ eoutB,
    const void* __restrict__ x_mask_o, const u16* __restrict__ x_maskB,
    const int* __restrict__ y,
    const void* __restrict__ y_mask_o, const u16* __restrict__ y_maskB,
    const void* __restrict__ emb_o, const u16* __restrict__ embB,
    const void* __restrict__ v_b_o, const u16* __restrict__ v_bB,
    const void* __restrict__ wav_o, const u16* __restrict__ wavB,
    const void* __restrict__ WihA_o, const u16* __restrict__ WihAB,
    const void* __restrict__ WhhA_o, const u16* __restrict__ WhhAB,
    const void* __restrict__ bihA_o, const u16* __restrict__ bihAB,
    const void* __restrict__ bhhA_o, const u16* __restrict__ bhhAB,
    const void* __restrict__ WihD_o, const u16* __restrict__ WihDB,
    const void* __restrict__ WhhD_o, const u16* __restrict__ WhhDB,
    const void* __restrict__ bihD_o, const u16* __restrict__ bihDB,
    const void* __restrict__ bhhD_o, const u16* __restrict__ bhhDB,
    u32* slots, float* h_dec, float* h_att,
    float* ctx_part, const u16* __restrict__ vwT, const u16* __restrict__ Ta,
    u16* __restrict__ dout) {
  // Named LDS arrays: 131072 + 16384 + 8192 + 8192 = 163840 B exactly.
  __shared__ u16 eout_l[65536];     // block's eout slice [256 t][256 d]
  __shared__ float x_l[8][512];
  __shared__ float h_l[8][256];
  __shared__ float scr[2048];
  // phase-2 scratch overlays x_l (lifetimes barrier-separated)
  float* sp     = (float*)x_l;          // 512 f
  float* hs_l   = (float*)x_l + 512;    // 256 f
  float* ts_l   = (float*)x_l + 768;    // 256 f
  float* p_l    = (float*)x_l + 1024;   // 256 f
  float* wv_l   = (float*)x_l + 1280;   // 256 f
  float* red_l  = (float*)x_l + 1536;   // 4 f
  float* inv_es = scr;                  // alive only before gemm clobbers scr
  float* ym_s   = scr + 8;

  const bool f32 = probe_f32(x_mask_o);
  const u16* eout   = f32 ? eoutB  : (const u16*)eout_o;
  const u16* x_mask = f32 ? x_maskB: (const u16*)x_mask_o;
  const u16* y_mask = f32 ? y_maskB: (const u16*)y_mask_o;
  const u16* emb    = f32 ? embB   : (const u16*)emb_o;
  const u16* v_b    = f32 ? v_bB   : (const u16*)v_b_o;
  const u16* wav    = f32 ? wavB   : (const u16*)wav_o;
  const u16* WihA   = f32 ? WihAB  : (const u16*)WihA_o;
  const u16* WhhA   = f32 ? WhhAB  : (const u16*)WhhA_o;
  const u16* bihA   = f32 ? bihAB  : (const u16*)bihA_o;
  const u16* bhhA   = f32 ? bhhAB  : (const u16*)bhhA_o;
  const u16* WihD   = f32 ? WihDB  : (const u16*)WihD_o;
  const u16* WhhD   = f32 ? WhhDB  : (const u16*)WhhD_o;
  const u16* bihD   = f32 ? bihDB  : (const u16*)bihD_o;
  const u16* bhhD   = f32 ? bhhDB  : (const u16*)bhhD_o;

  const int tid = threadIdx.x, blk = blockIdx.x;
  const int bg = blk >> 5, sub = blk & 31;
  const bool is_att = (sub < 16);
  const int hug = is_att ? sub : (sub - 16);
  const int b2 = blk >> 2, tc = blk & 3;
  const int pos = tid & 255, half = tid >> 8;

  float c_att_reg = 0.f;
  float c_dec_reg = 0.f;

  // per-thread step invariants
  const float xm_r = (bf2f(x_mask[b2 * 1024 + tc * 256 + pos]) - 1.f) * 1e30f;
  const float vb_r = bf2f(v_b[pos]);

  // ---- stage this block's eout slice (256 t x 256 d, bf16) into LDS ----
  // Linear row-major copy: coalesced uint4 global reads, linear LDS writes.
  {
    const u16* src = eout + (size_t)(b2 * 1024 + tc * 256) * 256;
#pragma unroll
    for (int k = 0; k < 16; ++k)
      ((uint4*)eout_l)[k * 512 + tid] = ((const uint4*)src)[k * 512 + tid];
  }
  __syncthreads();

  for (int t = 0; t <= 99; ++t) {
    if (is_att) {
      // per-batch invariant: softmax denominator reciprocal
      if (tid < 8 && t > 0) {
        const float* cp = ctx_part + (size_t)(bg * 8 + tid) * 4 * 257;
        float es = gload(cp + 256) + gload(cp + 257 + 256) +
                   gload(cp + 2 * 257 + 256) + gload(cp + 3 * 257 + 256);
        inv_es[tid] = 1.f / fmaxf(es, 1e-30f);
      }
      __syncthreads();
      for (int i = tid; i < 2048; i += 512) {
        int b = i >> 8, d = i & 255;
        int bglob = bg * 8 + b;
        int yv = y[bglob * 100 + t];
        x_l[b][d] = bf2f(emb[(size_t)yv * 256 + d]);
        float cx = 0.f;
        if (t > 0) {
          const float* cp = ctx_part + (size_t)bglob * 4 * 257;
          float s0 = gload(cp + d) + gload(cp + 257 + d) +
                     gload(cp + 2 * 257 + d) + gload(cp + 3 * 257 + d);
          cx = s0 * inv_es[b];
        }
        x_l[b][256 + d] = cx;
        h_l[b][d] = gload(h_att + (t & 1) * 16384 + bglob * 256 + d);
      }
      __syncthreads();
      if (t >= 1 && tid < 128) {
        int b = tid >> 4, dl = tid & 15;
        int bglob = bg * 8 + b, u = t - 1;
        float ym = bf2f(y_mask[bglob * 100 + u + 1]);
        float ym2 = ym * ym;
        int hu = hug * 16 + dl;
        size_t orow = ((size_t)bglob * 99 + u) * 768;
        dout[orow + hu] = f2bf(h_l[b][hu] * ym2);
        dout[orow + 256 + hu] = f2bf(x_l[b][256 + hu] * ym2);
      }
      if (t < 99) {
        p1_gemm(WihA, WhhA, x_l, h_l, scr, tid, hug);
        if (tid < 128) {
          int b = tid >> 4, dl = tid & 15;
          int bglob = bg * 8 + b;
          float g4[4];
#pragma unroll
          for (int gate = 0; gate < 4; ++gate) {
            int r2 = dl * 4 + gate;
            int wrow2 = gate * 256 + hug * 16 + dl;
            float sg = bf2f(bihA[wrow2]) + bf2f(bhhA[wrow2]);
#pragma unroll
            for (int q = 0; q < 4; ++q)
              sg += scr[r2 * 32 + ((b * 4 + q + r2) & 31)];
            g4[gate] = sg;
          }
          float ii = sigm(g4[0]), ff = sigm(g4[1]), gg = tanh_(g4[2]), oo = sigm(g4[3]);
          float cn = ff * c_att_reg + ii * gg;
          c_att_reg = cn;
          float hn = oo * tanh_(cn);
          gstore(h_att + ((t + 1) & 1) * 16384 + bglob * 256 + hug * 16 + dl, hn);
        }
      }
    } else {
      if (t >= 1) {
        int s = t - 1;
        if (tid < 8) {
          int bglob = bg * 8 + tid;
          const float* cp = ctx_part + (size_t)bglob * 4 * 257;
          float es = gload(cp + 256) + gload(cp + 257 + 256) +
                     gload(cp + 2 * 257 + 256) + gload(cp + 3 * 257 + 256);
          inv_es[tid] = 1.f / fmaxf(es, 1e-30f);
          ym_s[tid] = bf2f(y_mask[bglob * 100 + s + 1]);
        }
        __syncthreads();
        for (int i = tid; i < 2048; i += 512) {
          int b = i >> 8, d = i & 255;
          int bglob = bg * 8 + b;
          float ym = ym_s[b];
          const float* cp = ctx_part + (size_t)bglob * 4 * 257;
          float s0 = gload(cp + d) + gload(cp + 257 + d) +
                     gload(cp + 2 * 257 + d) + gload(cp + 3 * 257 + d);
          float cx = s0 * inv_es[b];
          x_l[b][d] = gload(h_att + (t & 1) * 16384 + bglob * 256 + d) * ym;
          x_l[b][256 + d] = cx * ym;
          h_l[b][d] = gload(h_dec + (s & 1) * 16384 + bglob * 256 + d);
        }
        __syncthreads();
        p1_gemm(WihD, WhhD, x_l, h_l, scr, tid, hug);
        if (tid < 128) {
          int b = tid >> 4, dl = tid & 15;
          int bglob = bg * 8 + b;
          float g4[4];
#pragma unroll
          for (int gate = 0; gate < 4; ++gate) {
            int r2 = dl * 4 + gate;
            int wrow2 = gate * 256 + hug * 16 + dl;
            float sg = bf2f(bihD[wrow2]) + bf2f(bhhD[wrow2]);
#pragma unroll
            for (int q = 0; q < 4; ++q)
              sg += scr[r2 * 32 + ((b * 4 + q + r2) & 31)];
            g4[gate] = sg;
          }
          float ii = sigm(g4[0]), ff = sigm(g4[1]), gg = tanh_(g4[2]), oo = sigm(g4[3]);
          float cn = ff * c_dec_reg + ii * gg;
          c_dec_reg = cn;
          float hn = oo * tanh_(cn);
          int hu_g = hug * 16 + dl;
          gstore(h_dec + ((s + 1) & 1) * 16384 + bglob * 256 + hu_g, hn);
          float ym = bf2f(y_mask[bglob * 100 + s + 1]);  // ym_s clobbered by scr
          dout[((size_t)bglob * 99 + s) * 768 + 512 + hu_g] = f2bf(hn * ym);
        }
      }
    }
    if (t == 99) break;
    gbar2(slots, (u32)(2 * t + 1));

    // -------- phase 2: scores + softmax + context (all 256 blocks) --------
    {
      int b = b2;
      if (tid < 256) {
        hs_l[tid] = gload(h_att + ((t + 1) & 1) * 16384 + b * 256 + tid);
        wv_l[tid] = bf2f(wav[tid]);   // overlay clobbered each step
      }
      __syncthreads();
      {  // st partial: thread (n=pos, half) does 128 k's (vwT columns)
        const u16* col = vwT + (size_t)(half * 128) * 256 + pos;
        float st = 0.f;
#pragma unroll 16
        for (int k = 0; k < 128; ++k)
          st += hs_l[half * 128 + k] * bf2f(col[(size_t)k * 256]);
        sp[tid] = st;
      }
      __syncthreads();
      if (tid < 256)
        ts_l[tid] = tanh_(sp[tid] + sp[tid + 256] + vb_r);
      __syncthreads();
      {  // score partial: thread (pos, half) does 128 d's, Ta rows (global)
        int tg = tc * 256 + pos;
        const u16* ar = Ta + ((size_t)(b * 1024 + tg)) * 256 + half * 128;
        float sacc = 0.f;
#pragma unroll 8
        for (int d8 = 0; d8 < 128; d8 += 8) {
          float af[8];
          bf8_to_f32(*(const uint4*)(ar + d8), af);
#pragma unroll
          for (int j = 0; j < 8; ++j) {
            int d = half * 128 + d8 + j;
            float tsv = ts_l[d], ta = af[j];
            float u = tsv + ta;
            float v = fmaf(tsv, ta, 1.f);
            sacc = fmaf(wv_l[d] * u, __builtin_amdgcn_rcpf(fmaxf(v, 1e-6f)), sacc);
          }
        }
        sp[tid] = sacc;
      }
      __syncthreads();
      if (tid < 256) {
        float s = sp[tid] + sp[tid + 256] + xm_r;
        s = fminf(s, 80.f);
        float p = __builtin_amdgcn_exp2f(s * LOG2E);
        p_l[tid] = p;
        float wsum = p;
#pragma unroll
        for (int off = 32; off; off >>= 1) wsum += __shfl_down(wsum, off);
        if ((tid & 63) == 0) red_l[tid >> 6] = wsum;
      }
      __syncthreads();
      {  // ctx partial from LDS eout slice: thread (d=pos, half), 128 tt's
        const u16* erow = eout_l + (size_t)(half * 128) * 256 + pos;
        float a0 = 0.f;
#pragma unroll 16
        for (int tt = 0; tt < 128; ++tt)
          a0 += p_l[half * 128 + tt] * bf2f(erow[tt * 256]);
        sp[tid] = a0;
      }
      __syncthreads();
      if (tid < 256) {
        float* cslot = ctx_part + (size_t)(b * 4 + tc) * 257;
        gstore(cslot + tid, sp[tid] + sp[tid + 256]);
        if (tid == 0)
          gstore(cslot + 256, red_l[0] + red_l[1] + red_l[2] + red_l[3]);
      }
    }
    gbar2(slots, (u32)(2 * t + 2));
  }
}

extern "C" void kernel_launch(void* const* d_in, const int* in_sizes, int n_in,
                              void* d_out, int out_size, void* d_ws, size_t ws_size,
                              hipStream_t stream) {
  (void)in_sizes; (void)n_in; (void)out_size; (void)ws_size;
  const void* eout    = d_in[0];
  const void* x_mask  = d_in[1];
  const int*  y       = (const int*)d_in[2];
  const void* y_mask  = d_in[3];
  const void* emb     = d_in[4];
  const void* w_w     = d_in[5];
  const void* w_b     = d_in[6];
  const void* v_w     = d_in[7];
  const void* v_b     = d_in[8];
  const void* w_att_v = d_in[9];
  const void* Wih_att = d_in[10];
  const void* Whh_att = d_in[11];
  const void* bih_att = d_in[12];
  const void* bhh_att = d_in[13];
  const void* Wih_dec = d_in[14];
  const void* Whh_dec = d_in[15];
  const void* bih_dec = d_in[16];
  const void* bhh_dec = d_in[17];
  const void* cls_w   = d_in[18];
  const void* cls_b   = d_in[19];
  const u32* probe = (const u32*)x_mask;

  // d_out scratch: Ta then eoutB (fp32 mode only). Dead before k_logit.
  u16* TaB   = (u16*)d_out;
  u16* eoutB = TaB + 16777216;

  // ws layout (bytes), total ~22.7 MB
  char* w = (char*)d_ws;
  u32*   slots    = (u32*)(w + 0);           // 32768, zeroed
  float* h_dec    = (float*)(w + 32768);     // 131072, zeroed
  float* h_att    = (float*)(w + 163840);    // 131072 (buf0 zeroed via ZB)
  const size_t ZB = 229376;                  // zeroes slots+h_dec+h_att buf0
  float* ctx_part = (float*)(w + 491520);    // 263168
  u16*   vwT      = (u16*)(w + 754688);      // 131072
  u16*   dout     = (u16*)(w + 885760);      // 9732096 -> 10617856
  u16*   embB     = (u16*)(w + 10617856);
  u16*   WihAB    = (u16*)(w + 12785152);
  u16*   WhhAB    = (u16*)(w + 13833728);
  u16*   WihDB    = (u16*)(w + 14358016);
  u16*   WhhDB    = (u16*)(w + 15406592);
  u16*   bihAB    = (u16*)(w + 15930880);
  u16*   bhhAB    = (u16*)(w + 15932928);
  u16*   bihDB    = (u16*)(w + 15934976);
  u16*   bhhDB    = (u16*)(w + 15937024);
  u16*   v_bB     = (u16*)(w + 15939072);
  u16*   wavB     = (u16*)(w + 15939584);
  u16*   w_wB     = (u16*)(w + 15940096);
  u16*   w_bB     = (u16*)(w + 16071168);
  u16*   x_maskB  = (u16*)(w + 16071680);
  u16*   y_maskB  = (u16*)(w + 16202752);
  u16*   cls_wB   = (u16*)(w + 16215552);
  u16*   cls_bB   = (u16*)(w + 22717440);

  Segs S;
  const void* srcs[NSEG] = {eout, emb, Wih_att, Whh_att, Wih_dec, Whh_dec,
                            bih_att, bhh_att, bih_dec, bhh_dec, v_b, w_att_v,
                            w_w, w_b, x_mask, y_mask, cls_w, cls_b};
  u16* dsts[NSEG] = {eoutB, embB, WihAB, WhhAB, WihDB, WhhDB,
                     bihAB, bhhAB, bihDB, bhhDB, v_bB, wavB,
                     w_wB, w_bB, x_maskB, y_maskB, cls_wB, cls_bB};
  int ns[NSEG] = {16777216, 1083648, 524288, 262144, 524288, 262144,
                  1024, 1024, 1024, 1024, 256, 256,
                  65536, 256, 65536, 6400, 3250944, 4233};
  for (int i = 0; i < NSEG; ++i) { S.src[i] = srcs[i]; S.dst[i] = dsts[i]; S.n[i] = ns[i]; }

  hipMemsetAsync(d_ws, 0, ZB, stream);
  hipLaunchKernelGGL(k_convert, dim3(4096, NSEG), dim3(256), 0, stream, S, probe);
  hipLaunchKernelGGL(k_vwt, dim3(256), dim3(256), 0, stream, v_w, vwT, probe);
  hipLaunchKernelGGL(k_atth, dim3(1024, 4), dim3(256), 0, stream,
                     eout, eoutB, w_w, w_wB, w_b, w_bB, TaB, probe);
  hipLaunchKernelGGL(k_scan, dim3(NBLK), dim3(512), 0, stream,
                     eout, eoutB, x_mask, x_maskB, y, y_mask, y_maskB,
                     emb, embB, v_b, v_bB, w_att_v, wavB,
                     Wih_att, WihAB, Whh_att, WhhAB, bih_att, bihAB, bhh_att, bhhAB,
                     Wih_dec, WihDB, Whh_dec, WhhDB, bih_dec, bihDB, bhh_dec, bhhDB,
                     slots, h_dec, h_att, ctx_part, vwT, TaB, dout);
  hipLaunchKernelGGL(k_logit, dim3(99, 67), dim3(256), 0, stream,
                     dout, cls_w, cls_wB, cls_b, cls_bB, d_out, probe);
}